// Round 8
// baseline (390.357 us; speedup 1.0000x reference)
//
#include <hip/hip_runtime.h>

typedef short bf16x8 __attribute__((ext_vector_type(8)));
typedef float f32x4  __attribute__((ext_vector_type(4)));

namespace {

constexpr int CIN = 32, CO = 32, Himg = 128, Wimg = 128, SY = 32, Bb = 4;
constexpr int IMG = Himg * Wimg;                 // 16384
constexpr int NT  = Bb * CO * IMG;               // new_target elems
constexpr size_t WS_NEED = (size_t)(Bb * SY + Bb) * IMG * CIN * 2;  // 138,412,032 B

__device__ __forceinline__ unsigned cvtpk(float lo, float hi) {
  unsigned r;
  asm("v_cvt_pk_bf16_f32 %0, %1, %2" : "=v"(r) : "v"(lo), "v"(hi));
  return r;
}

// per-lane A fragments (weights) for one co-tile m; ci = cioff + kc*8 + j
__device__ __forceinline__ void load_w(bf16x8 wf[9],
                                       const float* __restrict__ Wfull,
                                       int cioff, int m, int lane)
{
  const int lx = lane & 15, kc = lane >> 4;
  #pragma unroll
  for (int tap = 0; tap < 9; ++tap) {
    const float* base = Wfull + (size_t)((m * 16 + lx) * 64 + cioff + kc * 8) * 9 + tap;
    bf16x8 w;
    #pragma unroll
    for (int j = 0; j < 8; ++j) {
      unsigned u = __builtin_bit_cast(unsigned, base[j * 9]);
      w[j] = (short)((u + 0x7FFFu + ((u >> 16) & 1u)) >> 16);
    }
    wf[tap] = w;
  }
}

// ======================= kernel T: NCHW f32 -> NHWC bf16 =======================
// block = 256 thr, handles 2 rows of one image (132 images x 64 chunks = 8448)
__global__ __launch_bounds__(256)
void transform_nhwc(const float* __restrict__ target,
                    const float* __restrict__ support,
                    unsigned short* __restrict__ ws)
{
  __shared__ unsigned lbuf[256 * 17];   // [px(256)][c2(16)] swizzled, pad-free

  const int tid   = threadIdx.x;
  const int img   = blockIdx.x >> 6;
  const int chunk = blockIdx.x & 63;
  const float* src = (img < Bb * SY)
      ? support + (size_t)img * CIN * IMG
      : target  + (size_t)(img - Bb * SY) * CIN * IMG;
  const int y0 = chunk * 2;

  // phase R: 1024 tasks = c2(16) x quad(64); coalesced f32x4 plane reads
  f32x4 a[4], bv[4];
  #pragma unroll
  for (int k = 0; k < 4; ++k) {
    const int task = tid + k * 256;
    const int c2 = task >> 6, quad = task & 63;
    const float* p = src + (size_t)(2 * c2) * IMG + y0 * Wimg + quad * 4;
    a[k]  = *reinterpret_cast<const f32x4*>(p);
    bv[k] = *reinterpret_cast<const f32x4*>(p + IMG);
  }
  #pragma unroll
  for (int k = 0; k < 4; ++k) {
    const int task = tid + k * 256;
    const int c2 = task >> 6, quad = task & 63;
    #pragma unroll
    for (int e = 0; e < 4; ++e) {
      const int px = quad * 4 + e;
      lbuf[px * 17 + (c2 ^ ((px >> 2) & 15))] = cvtpk(a[k][e], bv[k][e]);
    }
  }
  __syncthreads();

  // phase W: coalesced uint4 stores of [px][ci] bf16
  unsigned* dst32 = reinterpret_cast<unsigned*>(
      ws + (size_t)img * IMG * CIN + (size_t)y0 * Wimg * CIN);
  #pragma unroll
  for (int j = 0; j < 4; ++j) {
    const int t4 = (tid + j * 256) * 4;
    uint4 v;
    unsigned* vp = reinterpret_cast<unsigned*>(&v);
    #pragma unroll
    for (int e = 0; e < 4; ++e) {
      const int t = t4 + e;
      const int px = t >> 4, c2 = t & 15;
      vp[e] = lbuf[px * 17 + (c2 ^ ((px >> 2) & 15))];
    }
    *reinterpret_cast<uint4*>(dst32 + t4) = v;
  }
}

// ======================= kernel C: barrier-free NHWC conv =======================
__device__ __forceinline__ void conv_img(f32x4 acc[4],
                                         const unsigned short* __restrict__ img,
                                         const bf16x8 wf[9],
                                         int y, int x0, int lx, int kc)
{
  #pragma unroll
  for (int ky = 0; ky < 3; ++ky) {
    const int yy = y + ky - 1;
    if ((unsigned)yy >= (unsigned)Himg) continue;          // wave-uniform skip
    const unsigned short* rowp = img + (size_t)yy * (Wimg * CIN) + kc * 8;
    #pragma unroll
    for (int kx = 0; kx < 3; ++kx) {
      #pragma unroll
      for (int n = 0; n < 4; ++n) {
        const int xx = x0 + n * 16 + lx + kx - 1;
        bf16x8 bf = {0, 0, 0, 0, 0, 0, 0, 0};
        if ((unsigned)xx < (unsigned)Wimg)
          bf = *reinterpret_cast<const bf16x8*>(rowp + xx * CIN);
        acc[n] = __builtin_amdgcn_mfma_f32_16x16x32_bf16(wf[ky * 3 + kx], bf, acc[n], 0, 0, 0);
      }
    }
  }
}

__global__ __launch_bounds__(256, 3)
void conv_nhwc(const unsigned short* __restrict__ ws,
               const float* __restrict__ Wfull,
               const float* __restrict__ bias,
               float* __restrict__ out)
{
  // bijective XCD swizzle: each XCD owns contiguous eff-ranges (image-set locality)
  const int orig = blockIdx.x;
  const int eff  = (orig & 7) * 256 + (orig >> 3);
  const int yb  = eff & 63;
  const int xh  = (eff >> 6) & 1;
  const int syq = (eff >> 7) & 3;
  const int b   = eff >> 9;

  const int tid = threadIdx.x, lane = tid & 63, wv = tid >> 6;
  const int row = wv & 1, m = wv >> 1;
  const int lx = lane & 15, kc = lane >> 4;
  const int y  = yb * 2 + row;
  const int x0 = xh * 64;

  const unsigned short* tgt  = ws + (size_t)(Bb * SY + b) * IMG * CIN;
  const unsigned short* sup0 = ws + (size_t)(b * SY + syq * 8) * IMG * CIN;

  bf16x8 wf[9];
  load_w(wf, Wfull, 0, m, lane);                  // Wx

  f32x4 cx[4];
  #pragma unroll
  for (int n = 0; n < 4; ++n) cx[n] = f32x4{0.f, 0.f, 0.f, 0.f};
  conv_img(cx, tgt, wf, y, x0, lx, kc);
  #pragma unroll
  for (int j = 0; j < 4; ++j) {
    const float bvv = bias[m * 16 + kc * 4 + j];
    #pragma unroll
    for (int n = 0; n < 4; ++n) cx[n][j] += bvv;
  }

  load_w(wf, Wfull, 32, m, lane);                 // Wy

  f32x4 sum[4];
  #pragma unroll
  for (int n = 0; n < 4; ++n) sum[n] = f32x4{0.f, 0.f, 0.f, 0.f};

  for (int i = 0; i < 8; ++i) {
    const int sy = syq * 8 + i;
    const unsigned short* img = sup0 + (size_t)i * IMG * CIN;

    f32x4 acc[4];
    #pragma unroll
    for (int n = 0; n < 4; ++n) acc[n] = cx[n];
    conv_img(acc, img, wf, y, x0, lx, kc);

    #pragma unroll
    for (int n = 0; n < 4; ++n) {
      sum[n] += acc[n];
      const size_t basei = (size_t)NT +
          (((size_t)(b * SY + sy) * CO + m * 16 + kc * 4) * Himg + y) * Wimg +
          x0 + n * 16 + lx;
      #pragma unroll
      for (int j = 0; j < 4; ++j)
        out[basei + (size_t)j * IMG] = acc[n][j];
    }
  }

  // new_target partial (4 syq partials per element)
  #pragma unroll
  for (int n = 0; n < 4; ++n) {
    const size_t baseo =
        ((size_t)(b * CO + m * 16 + kc * 4) * Himg + y) * Wimg + x0 + n * 16 + lx;
    #pragma unroll
    for (int j = 0; j < 4; ++j) {
      const float cyPart = (sum[n][j] - 8.f * cx[n][j]) * (1.f / 32.f);
      const float v = cyPart + (syq == 0 ? cx[n][j] : 0.f);
      atomicAdd(&out[baseo + (size_t)j * IMG], v);
    }
  }
}

// ======================= fallback (round-4 kernel, used if ws too small) =======================
constexpr int TROWS = 6, TQ = 17, TCOLS = 70;
constexpr int NPIX  = TROWS * TCOLS;
constexpr int LDSB  = NPIX * 64;
constexpr int RTASK = TROWS * TQ;
constexpr int FB_NTHR = 512;
constexpr int FB_TPT  = 4;
constexpr int FB_SYC  = 8;

__device__ __forceinline__ int fb_swz(int pix, int cb) {
  return (pix * 64 + cb) ^ ((pix & 7) << 4);
}
__device__ __forceinline__ void fb_task_decode(int t, int& ch, int& row, int& q, bool& act) {
  ch = t & 15;
  const int r = t >> 4;
  row = r / TQ;
  q   = r - row * TQ;
  act = (r < RTASK);
}
__device__ __forceinline__ void fb_stage_load(f32x4 va[FB_TPT], f32x4 vb[FB_TPT],
                                              const float* __restrict__ src,
                                              int y0, int xq0, int tid)
{
  #pragma unroll
  for (int k = 0; k < FB_TPT; ++k) {
    int ch, row, q; bool act;
    fb_task_decode(tid + k * FB_NTHR, ch, row, q, act);
    const int y = y0 - 1 + row;
    act = act && ((unsigned)y < (unsigned)Himg);
    f32x4 v0 = {0.f, 0.f, 0.f, 0.f}, v1 = {0.f, 0.f, 0.f, 0.f};
    if (act) {
      const float* p = src + (size_t)(2 * ch) * IMG + y * Wimg + 4 * (xq0 + q);
      v0 = *reinterpret_cast<const f32x4*>(p);
      v1 = *reinterpret_cast<const f32x4*>(p + IMG);
    }
    va[k] = v0; vb[k] = v1;
  }
}
__device__ __forceinline__ void fb_stage_write(const f32x4 va[FB_TPT], const f32x4 vb[FB_TPT],
                                               char* __restrict__ lds,
                                               int y0, int xq0, int x0, int tid)
{
  #pragma unroll
  for (int k = 0; k < FB_TPT; ++k) {
    int ch, row, q; bool act;
    fb_task_decode(tid + k * FB_NTHR, ch, row, q, act);
    const int y = y0 - 1 + row;
    act = act && ((unsigned)y < (unsigned)Himg);
    if (act) {
      const int ix0 = 4 * (xq0 + q) - x0 + 1;
      #pragma unroll
      for (int e = 0; e < 4; ++e) {
        const int ix = ix0 + e;
        if (ix >= 0) {
          const int pix = row * TCOLS + ix;
          *reinterpret_cast<unsigned*>(lds + fb_swz(pix, ch * 4)) =
              cvtpk(va[k][e], vb[k][e]);
        }
      }
    }
  }
}
__device__ __forceinline__ void fb_conv1(f32x4 acc[4],
                                         const char* __restrict__ lds,
                                         const bf16x8 wf[9],
                                         int row, int lane)
{
  const int lx = lane & 15, kc = lane >> 4;
  #pragma unroll
  for (int ky = 0; ky < 3; ++ky) {
    #pragma unroll
    for (int kx = 0; kx < 3; ++kx) {
      const int tap = ky * 3 + kx;
      #pragma unroll
      for (int n = 0; n < 4; ++n) {
        const int p = (row + ky) * TCOLS + n * 16 + lx + kx;
        const bf16x8 bfrag = *reinterpret_cast<const bf16x8*>(lds + fb_swz(p, kc * 16));
        acc[n] = __builtin_amdgcn_mfma_f32_16x16x32_bf16(wf[tap], bfrag, acc[n], 0, 0, 0);
      }
    }
  }
}
__global__ __launch_bounds__(FB_NTHR, 4)
void fb_cross_mfma(const float* __restrict__ target,
                   const float* __restrict__ support,
                   const float* __restrict__ Wfull,
                   const float* __restrict__ bias,
                   float* __restrict__ out)
{
  __shared__ char lds[LDSB];
  const int tid  = threadIdx.x;
  const int lane = tid & 63;
  const int wv   = tid >> 6;
  const int row  = wv & 3;
  const int m    = wv >> 2;
  const int lx = lane & 15, kc = lane >> 4;
  const int bid = blockIdx.x;
  const int syq = bid & 3;
  const int xh  = (bid >> 2) & 1;
  const int yb  = (bid >> 3) & 31;
  const int b   = bid >> 8;
  const int y0 = yb * 4, x0 = xh * 64;
  const int y  = y0 + row;
  const int xq0 = xh ? 15 : 0;

  for (int e = tid; e < NPIX * 4; e += FB_NTHR)
    reinterpret_cast<f32x4*>(lds)[e] = f32x4{0.f, 0.f, 0.f, 0.f};

  bf16x8 wf[9];
  load_w(wf, Wfull, 0, m, lane);
  f32x4 va[FB_TPT], vb[FB_TPT];
  fb_stage_load(va, vb, target + (size_t)b * CIN * IMG, y0, xq0, tid);
  __syncthreads();
  fb_stage_write(va, vb, lds, y0, xq0, x0, tid);
  __syncthreads();

  f32x4 cx[4];
  #pragma unroll
  for (int n = 0; n < 4; ++n) cx[n] = f32x4{0.f, 0.f, 0.f, 0.f};
  fb_conv1(cx, lds, wf, row, lane);
  #pragma unroll
  for (int j = 0; j < 4; ++j) {
    const float bvv = bias[m * 16 + kc * 4 + j];
    #pragma unroll
    for (int n = 0; n < 4; ++n) cx[n][j] += bvv;
  }

  const float* supp0 = support + (size_t)(b * SY + syq * FB_SYC) * CIN * IMG;
  fb_stage_load(va, vb, supp0, y0, xq0, tid);
  load_w(wf, Wfull, 32, m, lane);
  __syncthreads();
  fb_stage_write(va, vb, lds, y0, xq0, x0, tid);

  f32x4 sum[4];
  #pragma unroll
  for (int n = 0; n < 4; ++n) sum[n] = f32x4{0.f, 0.f, 0.f, 0.f};
  __syncthreads();

  for (int i = 0; i < FB_SYC; ++i) {
    if (i < FB_SYC - 1)
      fb_stage_load(va, vb, supp0 + (size_t)(i + 1) * CIN * IMG, y0, xq0, tid);

    f32x4 acc[4];
    #pragma unroll
    for (int n = 0; n < 4; ++n) acc[n] = cx[n];
    fb_conv1(acc, lds, wf, row, lane);
    __syncthreads();

    if (i < FB_SYC - 1)
      fb_stage_write(va, vb, lds, y0, xq0, x0, tid);

    const int sy = syq * FB_SYC + i;
    #pragma unroll
    for (int n = 0; n < 4; ++n) {
      sum[n] += acc[n];
      const size_t basei = (size_t)NT +
          (((size_t)(b * SY + sy) * CO + m * 16 + kc * 4) * Himg + y) * Wimg +
          x0 + n * 16 + lx;
      #pragma unroll
      for (int j = 0; j < 4; ++j)
        out[basei + (size_t)j * IMG] = acc[n][j];
    }
    __syncthreads();
  }

  #pragma unroll
  for (int n = 0; n < 4; ++n) {
    const size_t baseo =
        ((size_t)(b * CO + m * 16 + kc * 4) * Himg + y) * Wimg + x0 + n * 16 + lx;
    #pragma unroll
    for (int j = 0; j < 4; ++j) {
      const float cyPart = (sum[n][j] - (float)FB_SYC * cx[n][j]) * (1.f / 32.f);
      const float v = cyPart + (syq == 0 ? cx[n][j] : 0.f);
      atomicAdd(&out[baseo + (size_t)j * IMG], v);
    }
  }
}

} // namespace

extern "C" void kernel_launch(void* const* d_in, const int* in_sizes, int n_in,
                              void* d_out, int out_size, void* d_ws, size_t ws_size,
                              hipStream_t stream)
{
  (void)in_sizes; (void)n_in; (void)out_size;
  const float* target  = (const float*)d_in[0];
  const float* support = (const float*)d_in[1];
  const float* Wfull   = (const float*)d_in[2];
  const float* bias    = (const float*)d_in[3];
  float* out = (float*)d_out;

  hipMemsetAsync(d_out, 0, (size_t)NT * sizeof(float), stream);

  if (ws_size >= WS_NEED) {
    unsigned short* ws = (unsigned short*)d_ws;
    transform_nhwc<<<dim3((Bb * SY + Bb) * 64), 256, 0, stream>>>(target, support, ws);
    conv_nhwc<<<dim3(2048), 256, 0, stream>>>(ws, Wfull, bias, out);
  } else {
    fb_cross_mfma<<<dim3(1024), FB_NTHR, 0, stream>>>(target, support, Wfull, bias, out);
  }
}

// Round 9
// 378.107 us; speedup vs baseline: 1.0324x; 1.0324x over previous
//
#include <hip/hip_runtime.h>

typedef short bf16x8 __attribute__((ext_vector_type(8)));
typedef float f32x4  __attribute__((ext_vector_type(4)));

namespace {

constexpr int CIN = 32, CO = 32, Himg = 128, Wimg = 128, SY = 32, Bb = 4;
constexpr int IMG = Himg * Wimg;                 // 16384
constexpr int NT  = Bb * CO * IMG;               // new_target elems
constexpr size_t WS_NEED = (size_t)(Bb * SY + Bb) * IMG * CIN * 2;  // 138,412,032 B

__device__ __forceinline__ unsigned cvtpk(float lo, float hi) {
  unsigned r;
  asm("v_cvt_pk_bf16_f32 %0, %1, %2" : "=v"(r) : "v"(lo), "v"(hi));
  return r;
}

// per-lane A fragments (weights) for one co-tile m; ci = cioff + kc*8 + j
__device__ __forceinline__ void load_w(bf16x8 wf[9],
                                       const float* __restrict__ Wfull,
                                       int cioff, int m, int lane)
{
  const int lx = lane & 15, kc = lane >> 4;
  #pragma unroll
  for (int tap = 0; tap < 9; ++tap) {
    const float* base = Wfull + (size_t)((m * 16 + lx) * 64 + cioff + kc * 8) * 9 + tap;
    bf16x8 w;
    #pragma unroll
    for (int j = 0; j < 8; ++j) {
      unsigned u = __builtin_bit_cast(unsigned, base[j * 9]);
      w[j] = (short)((u + 0x7FFFu + ((u >> 16) & 1u)) >> 16);
    }
    wf[tap] = w;
  }
}

// ======================= kernel T: NCHW f32 -> NHWC bf16 =======================
// block = 256 thr, handles 2 rows of one image (132 images x 64 chunks = 8448)
__global__ __launch_bounds__(256)
void transform_nhwc(const float* __restrict__ target,
                    const float* __restrict__ support,
                    unsigned short* __restrict__ ws)
{
  __shared__ unsigned lbuf[256 * 17];   // [px(256)][c2(16)] swizzled, pad-free

  const int tid   = threadIdx.x;
  const int img   = blockIdx.x >> 6;
  const int chunk = blockIdx.x & 63;
  const float* src = (img < Bb * SY)
      ? support + (size_t)img * CIN * IMG
      : target  + (size_t)(img - Bb * SY) * CIN * IMG;
  const int y0 = chunk * 2;

  // phase R: 1024 tasks = c2(16) x quad(64); coalesced f32x4 plane reads
  f32x4 a[4], bv[4];
  #pragma unroll
  for (int k = 0; k < 4; ++k) {
    const int task = tid + k * 256;
    const int c2 = task >> 6, quad = task & 63;
    const float* p = src + (size_t)(2 * c2) * IMG + y0 * Wimg + quad * 4;
    a[k]  = *reinterpret_cast<const f32x4*>(p);
    bv[k] = *reinterpret_cast<const f32x4*>(p + IMG);
  }
  #pragma unroll
  for (int k = 0; k < 4; ++k) {
    const int task = tid + k * 256;
    const int c2 = task >> 6, quad = task & 63;
    #pragma unroll
    for (int e = 0; e < 4; ++e) {
      const int px = quad * 4 + e;
      lbuf[px * 17 + (c2 ^ ((px >> 2) & 15))] = cvtpk(a[k][e], bv[k][e]);
    }
  }
  __syncthreads();

  // phase W: coalesced uint4 stores of [px][ci] bf16
  unsigned* dst32 = reinterpret_cast<unsigned*>(
      ws + (size_t)img * IMG * CIN + (size_t)y0 * Wimg * CIN);
  #pragma unroll
  for (int j = 0; j < 4; ++j) {
    const int t4 = (tid + j * 256) * 4;
    uint4 v;
    unsigned* vp = reinterpret_cast<unsigned*>(&v);
    #pragma unroll
    for (int e = 0; e < 4; ++e) {
      const int t = t4 + e;
      const int px = t >> 4, c2 = t & 15;
      vp[e] = lbuf[px * 17 + (c2 ^ ((px >> 2) & 15))];
    }
    *reinterpret_cast<uint4*>(dst32 + t4) = v;
  }
}

// ======================= kernel C: barrier-free NHWC conv =======================
__device__ __forceinline__ void conv_img(f32x4 acc[4],
                                         const unsigned short* __restrict__ img,
                                         const bf16x8 wf[9],
                                         int y, int x0, int lx, int kc)
{
  #pragma unroll
  for (int ky = 0; ky < 3; ++ky) {
    const int yy = y + ky - 1;
    if ((unsigned)yy >= (unsigned)Himg) continue;          // wave-uniform skip
    const unsigned short* rowp = img + (size_t)yy * (Wimg * CIN) + kc * 8;
    #pragma unroll
    for (int kx = 0; kx < 3; ++kx) {
      #pragma unroll
      for (int n = 0; n < 4; ++n) {
        const int xx = x0 + n * 16 + lx + kx - 1;
        bf16x8 bf = {0, 0, 0, 0, 0, 0, 0, 0};
        if ((unsigned)xx < (unsigned)Wimg)
          bf = *reinterpret_cast<const bf16x8*>(rowp + xx * CIN);
        acc[n] = __builtin_amdgcn_mfma_f32_16x16x32_bf16(wf[ky * 3 + kx], bf, acc[n], 0, 0, 0);
      }
    }
  }
}

__global__ __launch_bounds__(256, 3)
void conv_nhwc(const unsigned short* __restrict__ ws,
               const float* __restrict__ Wfull,
               const float* __restrict__ bias,
               float* __restrict__ out)
{
  // bijective XCD swizzle: each XCD owns contiguous eff-ranges (image-set locality)
  const int orig = blockIdx.x;
  const int eff  = (orig & 7) * 256 + (orig >> 3);
  const int yb  = eff & 63;
  const int xh  = (eff >> 6) & 1;
  const int syq = (eff >> 7) & 3;
  const int b   = eff >> 9;

  const int tid = threadIdx.x, lane = tid & 63, wv = tid >> 6;
  const int row = wv & 1, m = wv >> 1;
  const int lx = lane & 15, kc = lane >> 4;
  const int y  = yb * 2 + row;
  const int x0 = xh * 64;

  const unsigned short* tgt  = ws + (size_t)(Bb * SY + b) * IMG * CIN;
  const unsigned short* sup0 = ws + (size_t)(b * SY + syq * 8) * IMG * CIN;

  bf16x8 wf[9];
  load_w(wf, Wfull, 0, m, lane);                  // Wx

  f32x4 cx[4];
  #pragma unroll
  for (int n = 0; n < 4; ++n) cx[n] = f32x4{0.f, 0.f, 0.f, 0.f};
  conv_img(cx, tgt, wf, y, x0, lx, kc);
  #pragma unroll
  for (int j = 0; j < 4; ++j) {
    const float bvv = bias[m * 16 + kc * 4 + j];
    #pragma unroll
    for (int n = 0; n < 4; ++n) cx[n][j] += bvv;
  }

  load_w(wf, Wfull, 32, m, lane);                 // Wy

  f32x4 sum[4];
  #pragma unroll
  for (int n = 0; n < 4; ++n) sum[n] = f32x4{0.f, 0.f, 0.f, 0.f};

  for (int i = 0; i < 8; ++i) {
    const int sy = syq * 8 + i;
    const unsigned short* img = sup0 + (size_t)i * IMG * CIN;

    f32x4 acc[4];
    #pragma unroll
    for (int n = 0; n < 4; ++n) acc[n] = cx[n];
    conv_img(acc, img, wf, y, x0, lx, kc);

    #pragma unroll
    for (int n = 0; n < 4; ++n) {
      sum[n] += acc[n];
      const size_t basei = (size_t)NT +
          (((size_t)(b * SY + sy) * CO + m * 16 + kc * 4) * Himg + y) * Wimg +
          x0 + n * 16 + lx;
      #pragma unroll
      for (int j = 0; j < 4; ++j)
        out[basei + (size_t)j * IMG] = acc[n][j];
    }
  }

  // new_target partial (4 syq partials per element)
  #pragma unroll
  for (int n = 0; n < 4; ++n) {
    const size_t baseo =
        ((size_t)(b * CO + m * 16 + kc * 4) * Himg + y) * Wimg + x0 + n * 16 + lx;
    #pragma unroll
    for (int j = 0; j < 4; ++j) {
      const float cyPart = (sum[n][j] - 8.f * cx[n][j]) * (1.f / 32.f);
      const float v = cyPart + (syq == 0 ? cx[n][j] : 0.f);
      atomicAdd(&out[baseo + (size_t)j * IMG], v);
    }
  }
}

// ======================= fallback (round-4 kernel, used if ws too small) =======================
constexpr int TROWS = 6, TQ = 17, TCOLS = 70;
constexpr int NPIX  = TROWS * TCOLS;
constexpr int LDSB  = NPIX * 64;
constexpr int RTASK = TROWS * TQ;
constexpr int FB_NTHR = 512;
constexpr int FB_TPT  = 4;
constexpr int FB_SYC  = 8;

__device__ __forceinline__ int fb_swz(int pix, int cb) {
  return (pix * 64 + cb) ^ ((pix & 7) << 4);
}
__device__ __forceinline__ void fb_task_decode(int t, int& ch, int& row, int& q, bool& act) {
  ch = t & 15;
  const int r = t >> 4;
  row = r / TQ;
  q   = r - row * TQ;
  act = (r < RTASK);
}
__device__ __forceinline__ void fb_stage_load(f32x4 va[FB_TPT], f32x4 vb[FB_TPT],
                                              const float* __restrict__ src,
                                              int y0, int xq0, int tid)
{
  #pragma unroll
  for (int k = 0; k < FB_TPT; ++k) {
    int ch, row, q; bool act;
    fb_task_decode(tid + k * FB_NTHR, ch, row, q, act);
    const int y = y0 - 1 + row;
    act = act && ((unsigned)y < (unsigned)Himg);
    f32x4 v0 = {0.f, 0.f, 0.f, 0.f}, v1 = {0.f, 0.f, 0.f, 0.f};
    if (act) {
      const float* p = src + (size_t)(2 * ch) * IMG + y * Wimg + 4 * (xq0 + q);
      v0 = *reinterpret_cast<const f32x4*>(p);
      v1 = *reinterpret_cast<const f32x4*>(p + IMG);
    }
    va[k] = v0; vb[k] = v1;
  }
}
__device__ __forceinline__ void fb_stage_write(const f32x4 va[FB_TPT], const f32x4 vb[FB_TPT],
                                               char* __restrict__ lds,
                                               int y0, int xq0, int x0, int tid)
{
  #pragma unroll
  for (int k = 0; k < FB_TPT; ++k) {
    int ch, row, q; bool act;
    fb_task_decode(tid + k * FB_NTHR, ch, row, q, act);
    const int y = y0 - 1 + row;
    act = act && ((unsigned)y < (unsigned)Himg);
    if (act) {
      const int ix0 = 4 * (xq0 + q) - x0 + 1;
      #pragma unroll
      for (int e = 0; e < 4; ++e) {
        const int ix = ix0 + e;
        if (ix >= 0) {
          const int pix = row * TCOLS + ix;
          *reinterpret_cast<unsigned*>(lds + fb_swz(pix, ch * 4)) =
              cvtpk(va[k][e], vb[k][e]);
        }
      }
    }
  }
}
__device__ __forceinline__ void fb_conv1(f32x4 acc[4],
                                         const char* __restrict__ lds,
                                         const bf16x8 wf[9],
                                         int row, int lane)
{
  const int lx = lane & 15, kc = lane >> 4;
  #pragma unroll
  for (int ky = 0; ky < 3; ++ky) {
    #pragma unroll
    for (int kx = 0; kx < 3; ++kx) {
      const int tap = ky * 3 + kx;
      #pragma unroll
      for (int n = 0; n < 4; ++n) {
        const int p = (row + ky) * TCOLS + n * 16 + lx + kx;
        const bf16x8 bfrag = *reinterpret_cast<const bf16x8*>(lds + fb_swz(p, kc * 16));
        acc[n] = __builtin_amdgcn_mfma_f32_16x16x32_bf16(wf[tap], bfrag, acc[n], 0, 0, 0);
      }
    }
  }
}
__global__ __launch_bounds__(FB_NTHR, 4)
void fb_cross_mfma(const float* __restrict__ target,
                   const float* __restrict__ support,
                   const float* __restrict__ Wfull,
                   const float* __restrict__ bias,
                   float* __restrict__ out)
{
  __shared__ char lds[LDSB];
  const int tid  = threadIdx.x;
  const int lane = tid & 63;
  const int wv   = tid >> 6;
  const int row  = wv & 3;
  const int m    = wv >> 2;
  const int lx = lane & 15, kc = lane >> 4;
  const int bid = blockIdx.x;
  const int syq = bid & 3;
  const int xh  = (bid >> 2) & 1;
  const int yb  = (bid >> 3) & 31;
  const int b   = bid >> 8;
  const int y0 = yb * 4, x0 = xh * 64;
  const int y  = y0 + row;
  const int xq0 = xh ? 15 : 0;

  for (int e = tid; e < NPIX * 4; e += FB_NTHR)
    reinterpret_cast<f32x4*>(lds)[e] = f32x4{0.f, 0.f, 0.f, 0.f};

  bf16x8 wf[9];
  load_w(wf, Wfull, 0, m, lane);
  f32x4 va[FB_TPT], vb[FB_TPT];
  fb_stage_load(va, vb, target + (size_t)b * CIN * IMG, y0, xq0, tid);
  __syncthreads();
  fb_stage_write(va, vb, lds, y0, xq0, x0, tid);
  __syncthreads();

  f32x4 cx[4];
  #pragma unroll
  for (int n = 0; n < 4; ++n) cx[n] = f32x4{0.f, 0.f, 0.f, 0.f};
  fb_conv1(cx, lds, wf, row, lane);
  #pragma unroll
  for (int j = 0; j < 4; ++j) {
    const float bvv = bias[m * 16 + kc * 4 + j];
    #pragma unroll
    for (int n = 0; n < 4; ++n) cx[n][j] += bvv;
  }

  const float* supp0 = support + (size_t)(b * SY + syq * FB_SYC) * CIN * IMG;
  fb_stage_load(va, vb, supp0, y0, xq0, tid);
  load_w(wf, Wfull, 32, m, lane);
  __syncthreads();
  fb_stage_write(va, vb, lds, y0, xq0, x0, tid);

  f32x4 sum[4];
  #pragma unroll
  for (int n = 0; n < 4; ++n) sum[n] = f32x4{0.f, 0.f, 0.f, 0.f};
  __syncthreads();

  for (int i = 0; i < FB_SYC; ++i) {
    if (i < FB_SYC - 1)
      fb_stage_load(va, vb, supp0 + (size_t)(i + 1) * CIN * IMG, y0, xq0, tid);

    f32x4 acc[4];
    #pragma unroll
    for (int n = 0; n < 4; ++n) acc[n] = cx[n];
    fb_conv1(acc, lds, wf, row, lane);
    __syncthreads();

    if (i < FB_SYC - 1)
      fb_stage_write(va, vb, lds, y0, xq0, x0, tid);

    const int sy = syq * FB_SYC + i;
    #pragma unroll
    for (int n = 0; n < 4; ++n) {
      sum[n] += acc[n];
      const size_t basei = (size_t)NT +
          (((size_t)(b * SY + sy) * CO + m * 16 + kc * 4) * Himg + y) * Wimg +
          x0 + n * 16 + lx;
      #pragma unroll
      for (int j = 0; j < 4; ++j)
        out[basei + (size_t)j * IMG] = acc[n][j];
    }
    __syncthreads();
  }

  #pragma unroll
  for (int n = 0; n < 4; ++n) {
    const size_t baseo =
        ((size_t)(b * CO + m * 16 + kc * 4) * Himg + y) * Wimg + x0 + n * 16 + lx;
    #pragma unroll
    for (int j = 0; j < 4; ++j) {
      const float cyPart = (sum[n][j] - (float)FB_SYC * cx[n][j]) * (1.f / 32.f);
      const float v = cyPart + (syq == 0 ? cx[n][j] : 0.f);
      atomicAdd(&out[baseo + (size_t)j * IMG], v);
    }
  }
}

} // namespace

extern "C" void kernel_launch(void* const* d_in, const int* in_sizes, int n_in,
                              void* d_out, int out_size, void* d_ws, size_t ws_size,
                              hipStream_t stream)
{
  (void)in_sizes; (void)n_in; (void)out_size;
  const float* target  = (const float*)d_in[0];
  const float* support = (const float*)d_in[1];
  const float* Wfull   = (const float*)d_in[2];
  const float* bias    = (const float*)d_in[3];
  float* out = (float*)d_out;

  hipMemsetAsync(d_out, 0, (size_t)NT * sizeof(float), stream);

  if (ws_size >= WS_NEED) {
    unsigned short* ws = (unsigned short*)d_ws;
    transform_nhwc<<<dim3((Bb * SY + Bb) * 64), 256, 0, stream>>>(target, support, ws);
    conv_nhwc<<<dim3(2048), 256, 0, stream>>>(ws, Wfull, bias, out);
  } else {
    fb_cross_mfma<<<dim3(1024), FB_NTHR, 0, stream>>>(target, support, Wfull, bias, out);
  }
}

// Round 10
// 337.045 us; speedup vs baseline: 1.1582x; 1.1218x over previous
//
#include <hip/hip_runtime.h>

typedef short bf16x8 __attribute__((ext_vector_type(8)));
typedef float f32x4  __attribute__((ext_vector_type(4)));

namespace {

constexpr int CIN = 32, CO = 32, Himg = 128, Wimg = 128, SY = 32, Bb = 4;
constexpr int IMG = Himg * Wimg;                 // 16384
constexpr int NT  = Bb * CO * IMG;               // new_target elems
constexpr int RS  = Wimg * CIN;                  // 4096 shorts per NHWC row
constexpr size_t IS = (size_t)IMG * CIN;         // 524288 shorts per image
constexpr size_t WS_NEED = (size_t)(Bb * SY + Bb) * IS * 2;  // 138,412,032 B

__device__ __forceinline__ unsigned cvtpk(float lo, float hi) {
  unsigned r;
  asm("v_cvt_pk_bf16_f32 %0, %1, %2" : "=v"(r) : "v"(lo), "v"(hi));
  return r;
}

// per-lane A fragments (weights) for one co-tile m; ci = cioff + kc*8 + j
__device__ __forceinline__ void load_w(bf16x8 wf[9],
                                       const float* __restrict__ Wfull,
                                       int cioff, int m, int lane)
{
  const int lx = lane & 15, kc = lane >> 4;
  #pragma unroll
  for (int tap = 0; tap < 9; ++tap) {
    const float* base = Wfull + (size_t)((m * 16 + lx) * 64 + cioff + kc * 8) * 9 + tap;
    bf16x8 w;
    #pragma unroll
    for (int j = 0; j < 8; ++j) {
      unsigned u = __builtin_bit_cast(unsigned, base[j * 9]);
      w[j] = (short)((u + 0x7FFFu + ((u >> 16) & 1u)) >> 16);
    }
    wf[tap] = w;
  }
}

// ======================= kernel T: NCHW f32 -> NHWC bf16 =======================
__global__ __launch_bounds__(256)
void transform_nhwc(const float* __restrict__ target,
                    const float* __restrict__ support,
                    unsigned short* __restrict__ ws)
{
  __shared__ unsigned lbuf[256 * 17];

  const int tid   = threadIdx.x;
  const int img   = blockIdx.x >> 6;
  const int chunk = blockIdx.x & 63;
  const float* src = (img < Bb * SY)
      ? support + (size_t)img * CIN * IMG
      : target  + (size_t)(img - Bb * SY) * CIN * IMG;
  const int y0 = chunk * 2;

  f32x4 a[4], bv[4];
  #pragma unroll
  for (int k = 0; k < 4; ++k) {
    const int task = tid + k * 256;
    const int c2 = task >> 6, quad = task & 63;
    const float* p = src + (size_t)(2 * c2) * IMG + y0 * Wimg + quad * 4;
    a[k]  = *reinterpret_cast<const f32x4*>(p);
    bv[k] = *reinterpret_cast<const f32x4*>(p + IMG);
  }
  #pragma unroll
  for (int k = 0; k < 4; ++k) {
    const int task = tid + k * 256;
    const int c2 = task >> 6, quad = task & 63;
    #pragma unroll
    for (int e = 0; e < 4; ++e) {
      const int px = quad * 4 + e;
      lbuf[px * 17 + (c2 ^ ((px >> 2) & 15))] = cvtpk(a[k][e], bv[k][e]);
    }
  }
  __syncthreads();

  unsigned* dst32 = reinterpret_cast<unsigned*>(
      ws + (size_t)img * IS + (size_t)y0 * RS);
  #pragma unroll
  for (int j = 0; j < 4; ++j) {
    const int t4 = (tid + j * 256) * 4;
    uint4 v;
    unsigned* vp = reinterpret_cast<unsigned*>(&v);
    #pragma unroll
    for (int e = 0; e < 4; ++e) {
      const int t = t4 + e;
      const int px = t >> 4, c2 = t & 15;
      vp[e] = lbuf[px * 17 + (c2 ^ ((px >> 2) & 15))];
    }
    *reinterpret_cast<uint4*>(dst32 + t4) = v;
  }
}

// ======================= kernel C: 2-row-reuse NHWC conv =======================
__device__ __forceinline__ bf16x8 ldf(const unsigned short* __restrict__ rowp, int px) {
  return *reinterpret_cast<const bf16x8*>(rowp + (size_t)px * CIN);
}
__device__ __forceinline__ bf16x8 ldfe(const unsigned short* __restrict__ rowp, int px) {
  const int pxc = px < 0 ? 0 : (px > 127 ? 127 : px);
  bf16x8 v = *reinterpret_cast<const bf16x8*>(rowp + (size_t)pxc * CIN);
  if (px != pxc) v = bf16x8{0, 0, 0, 0, 0, 0, 0, 0};
  return v;
}

// 6 fragments of one input row: F[n*3+kx], 16-px window at x0l + n*16 + kx - 1
__device__ __forceinline__ void loadrow(bf16x8 F[6],
                                        const unsigned short* __restrict__ rowp,
                                        int x0l)
{
  #pragma unroll
  for (int n = 0; n < 2; ++n)
    #pragma unroll
    for (int kx = 0; kx < 3; ++kx) {
      const int px = x0l + n * 16 + kx - 1;
      if ((n == 0 && kx == 0) || (n == 1 && kx == 2))
        F[n * 3 + kx] = ldfe(rowp, px);
      else
        F[n * 3 + kx] = ldf(rowp, px);
    }
}

// one tap-row of MFMAs: acc[n] += wt[kx] * F[n*3+kx]
__device__ __forceinline__ void mrow(f32x4 acc[2], const bf16x8 F[6], const bf16x8* wt) {
  #pragma unroll
  for (int kx = 0; kx < 3; ++kx)
    #pragma unroll
    for (int n = 0; n < 2; ++n)
      acc[n] = __builtin_amdgcn_mfma_f32_16x16x32_bf16(wt[kx], F[n * 3 + kx], acc[n], 0, 0, 0);
}

// conv one image, 2 output rows (y, y+1): input rows rc[0..3] (clamped y-1..y+2)
__device__ __forceinline__ void conv2rows(f32x4 acc[2][2],
                                          const unsigned short* __restrict__ imgp,
                                          const bf16x8 wf[9],
                                          const int rc[4], bool rok0, bool rok3,
                                          int x0l)
{
  bf16x8 A[6], Bq[6], Cq[6], Dq[6];
  loadrow(A,  imgp + (size_t)rc[0] * RS, x0l);
  loadrow(Bq, imgp + (size_t)rc[1] * RS, x0l);
  if (rok0) mrow(acc[0], A, wf + 0);          // r=y-1 -> out0, ky=0
  loadrow(Cq, imgp + (size_t)rc[2] * RS, x0l);
  mrow(acc[0], Bq, wf + 3);                   // r=y   -> out0, ky=1
  mrow(acc[1], Bq, wf + 0);                   //       -> out1, ky=0
  loadrow(Dq, imgp + (size_t)rc[3] * RS, x0l);
  mrow(acc[0], Cq, wf + 6);                   // r=y+1 -> out0, ky=2
  mrow(acc[1], Cq, wf + 3);                   //       -> out1, ky=1
  if (rok3) mrow(acc[1], Dq, wf + 6);         // r=y+2 -> out1, ky=2
}

__global__ __launch_bounds__(256, 3)
void conv_nhwc2(const unsigned short* __restrict__ ws,
                const float* __restrict__ Wfull,
                const float* __restrict__ bias,
                float* __restrict__ out)
{
  // bijective XCD swizzle (2048 % 8 == 0): ypair fastest for L2 row locality
  const int orig = blockIdx.x;
  const int eff  = (orig & 7) * 256 + (orig >> 3);
  const int yp  = eff & 63;
  const int xh  = (eff >> 6) & 1;
  const int syq = (eff >> 7) & 3;
  const int b   = eff >> 9;

  const int tid = threadIdx.x, lane = tid & 63, wv = tid >> 6;
  const int xq = wv & 1, m = wv >> 1;
  const int lx = lane & 15, kc = lane >> 4;
  const int y  = yp * 2;
  const int x0 = xh * 64 + xq * 32;
  const int x0l = x0 + lx;

  int rc[4];
  #pragma unroll
  for (int k = 0; k < 4; ++k) {
    int r = y - 1 + k;
    rc[k] = r < 0 ? 0 : (r > 127 ? 127 : r);
  }
  const bool rok0 = (y != 0), rok3 = (y != 126);

  const unsigned short* tgt  = ws + (size_t)(Bb * SY + b) * IS + kc * 8;
  const unsigned short* sup0 = ws + (size_t)(b * SY + syq * 8) * IS + kc * 8;

  bf16x8 wf[9];
  load_w(wf, Wfull, 0, m, lane);                  // Wx

  f32x4 cx[2][2];
  #pragma unroll
  for (int r2 = 0; r2 < 2; ++r2)
    #pragma unroll
    for (int n = 0; n < 2; ++n) cx[r2][n] = f32x4{0.f, 0.f, 0.f, 0.f};
  conv2rows(cx, tgt, wf, rc, rok0, rok3, x0l);
  #pragma unroll
  for (int j = 0; j < 4; ++j) {
    const float bvv = bias[m * 16 + kc * 4 + j];
    #pragma unroll
    for (int r2 = 0; r2 < 2; ++r2)
      #pragma unroll
      for (int n = 0; n < 2; ++n) cx[r2][n][j] += bvv;
  }

  load_w(wf, Wfull, 32, m, lane);                 // Wy

  f32x4 sum[2][2];
  #pragma unroll
  for (int r2 = 0; r2 < 2; ++r2)
    #pragma unroll
    for (int n = 0; n < 2; ++n) sum[r2][n] = f32x4{0.f, 0.f, 0.f, 0.f};

  for (int i = 0; i < 8; ++i) {
    const int sy = syq * 8 + i;

    f32x4 acc[2][2];
    #pragma unroll
    for (int r2 = 0; r2 < 2; ++r2)
      #pragma unroll
      for (int n = 0; n < 2; ++n) acc[r2][n] = cx[r2][n];
    conv2rows(acc, sup0 + (size_t)i * IS, wf, rc, rok0, rok3, x0l);

    #pragma unroll
    for (int r2 = 0; r2 < 2; ++r2)
      #pragma unroll
      for (int n = 0; n < 2; ++n) {
        sum[r2][n] += acc[r2][n];
        const size_t basei = (size_t)NT +
            (((size_t)(b * SY + sy) * CO + m * 16 + kc * 4) * Himg + y + r2) * Wimg +
            x0 + n * 16 + lx;
        #pragma unroll
        for (int j = 0; j < 4; ++j)
          out[basei + (size_t)j * IMG] = acc[r2][n][j];
      }
  }

  // new_target partial (4 syq partials per element)
  #pragma unroll
  for (int r2 = 0; r2 < 2; ++r2)
    #pragma unroll
    for (int n = 0; n < 2; ++n) {
      const size_t baseo =
          ((size_t)(b * CO + m * 16 + kc * 4) * Himg + y + r2) * Wimg + x0 + n * 16 + lx;
      #pragma unroll
      for (int j = 0; j < 4; ++j) {
        const float cyPart = (sum[r2][n][j] - 8.f * cx[r2][n][j]) * (1.f / 32.f);
        const float v = cyPart + (syq == 0 ? cx[r2][n][j] : 0.f);
        atomicAdd(&out[baseo + (size_t)j * IMG], v);
      }
    }
}

// ======================= fallback (round-4 kernel, used if ws too small) =======================
constexpr int TROWS = 6, TQ = 17, TCOLS = 70;
constexpr int NPIX  = TROWS * TCOLS;
constexpr int LDSB  = NPIX * 64;
constexpr int RTASK = TROWS * TQ;
constexpr int FB_NTHR = 512;
constexpr int FB_TPT  = 4;
constexpr int FB_SYC  = 8;

__device__ __forceinline__ int fb_swz(int pix, int cb) {
  return (pix * 64 + cb) ^ ((pix & 7) << 4);
}
__device__ __forceinline__ void fb_task_decode(int t, int& ch, int& row, int& q, bool& act) {
  ch = t & 15;
  const int r = t >> 4;
  row = r / TQ;
  q   = r - row * TQ;
  act = (r < RTASK);
}
__device__ __forceinline__ void fb_stage_load(f32x4 va[FB_TPT], f32x4 vb[FB_TPT],
                                              const float* __restrict__ src,
                                              int y0, int xq0, int tid)
{
  #pragma unroll
  for (int k = 0; k < FB_TPT; ++k) {
    int ch, row, q; bool act;
    fb_task_decode(tid + k * FB_NTHR, ch, row, q, act);
    const int y = y0 - 1 + row;
    act = act && ((unsigned)y < (unsigned)Himg);
    f32x4 v0 = {0.f, 0.f, 0.f, 0.f}, v1 = {0.f, 0.f, 0.f, 0.f};
    if (act) {
      const float* p = src + (size_t)(2 * ch) * IMG + y * Wimg + 4 * (xq0 + q);
      v0 = *reinterpret_cast<const f32x4*>(p);
      v1 = *reinterpret_cast<const f32x4*>(p + IMG);
    }
    va[k] = v0; vb[k] = v1;
  }
}
__device__ __forceinline__ void fb_stage_write(const f32x4 va[FB_TPT], const f32x4 vb[FB_TPT],
                                               char* __restrict__ lds,
                                               int y0, int xq0, int x0, int tid)
{
  #pragma unroll
  for (int k = 0; k < FB_TPT; ++k) {
    int ch, row, q; bool act;
    fb_task_decode(tid + k * FB_NTHR, ch, row, q, act);
    const int y = y0 - 1 + row;
    act = act && ((unsigned)y < (unsigned)Himg);
    if (act) {
      const int ix0 = 4 * (xq0 + q) - x0 + 1;
      #pragma unroll
      for (int e = 0; e < 4; ++e) {
        const int ix = ix0 + e;
        if (ix >= 0) {
          const int pix = row * TCOLS + ix;
          *reinterpret_cast<unsigned*>(lds + fb_swz(pix, ch * 4)) =
              cvtpk(va[k][e], vb[k][e]);
        }
      }
    }
  }
}
__device__ __forceinline__ void fb_conv1(f32x4 acc[4],
                                         const char* __restrict__ lds,
                                         const bf16x8 wf[9],
                                         int row, int lane)
{
  const int lx = lane & 15, kc = lane >> 4;
  #pragma unroll
  for (int ky = 0; ky < 3; ++ky) {
    #pragma unroll
    for (int kx = 0; kx < 3; ++kx) {
      const int tap = ky * 3 + kx;
      #pragma unroll
      for (int n = 0; n < 4; ++n) {
        const int p = (row + ky) * TCOLS + n * 16 + lx + kx;
        const bf16x8 bfrag = *reinterpret_cast<const bf16x8*>(lds + fb_swz(p, kc * 16));
        acc[n] = __builtin_amdgcn_mfma_f32_16x16x32_bf16(wf[tap], bfrag, acc[n], 0, 0, 0);
      }
    }
  }
}
__global__ __launch_bounds__(FB_NTHR, 4)
void fb_cross_mfma(const float* __restrict__ target,
                   const float* __restrict__ support,
                   const float* __restrict__ Wfull,
                   const float* __restrict__ bias,
                   float* __restrict__ out)
{
  __shared__ char lds[LDSB];
  const int tid  = threadIdx.x;
  const int lane = tid & 63;
  const int wv   = tid >> 6;
  const int row  = wv & 3;
  const int m    = wv >> 2;
  const int lx = lane & 15, kc = lane >> 4;
  const int bid = blockIdx.x;
  const int syq = bid & 3;
  const int xh  = (bid >> 2) & 1;
  const int yb  = (bid >> 3) & 31;
  const int b   = bid >> 8;
  const int y0 = yb * 4, x0 = xh * 64;
  const int y  = y0 + row;
  const int xq0 = xh ? 15 : 0;

  for (int e = tid; e < NPIX * 4; e += FB_NTHR)
    reinterpret_cast<f32x4*>(lds)[e] = f32x4{0.f, 0.f, 0.f, 0.f};

  bf16x8 wf[9];
  load_w(wf, Wfull, 0, m, lane);
  f32x4 va[FB_TPT], vb[FB_TPT];
  fb_stage_load(va, vb, target + (size_t)b * CIN * IMG, y0, xq0, tid);
  __syncthreads();
  fb_stage_write(va, vb, lds, y0, xq0, x0, tid);
  __syncthreads();

  f32x4 cx[4];
  #pragma unroll
  for (int n = 0; n < 4; ++n) cx[n] = f32x4{0.f, 0.f, 0.f, 0.f};
  fb_conv1(cx, lds, wf, row, lane);
  #pragma unroll
  for (int j = 0; j < 4; ++j) {
    const float bvv = bias[m * 16 + kc * 4 + j];
    #pragma unroll
    for (int n = 0; n < 4; ++n) cx[n][j] += bvv;
  }

  const float* supp0 = support + (size_t)(b * SY + syq * FB_SYC) * CIN * IMG;
  fb_stage_load(va, vb, supp0, y0, xq0, tid);
  load_w(wf, Wfull, 32, m, lane);
  __syncthreads();
  fb_stage_write(va, vb, lds, y0, xq0, x0, tid);

  f32x4 sum[4];
  #pragma unroll
  for (int n = 0; n < 4; ++n) sum[n] = f32x4{0.f, 0.f, 0.f, 0.f};
  __syncthreads();

  for (int i = 0; i < FB_SYC; ++i) {
    if (i < FB_SYC - 1)
      fb_stage_load(va, vb, supp0 + (size_t)(i + 1) * CIN * IMG, y0, xq0, tid);

    f32x4 acc[4];
    #pragma unroll
    for (int n = 0; n < 4; ++n) acc[n] = cx[n];
    fb_conv1(acc, lds, wf, row, lane);
    __syncthreads();

    if (i < FB_SYC - 1)
      fb_stage_write(va, vb, lds, y0, xq0, x0, tid);

    const int sy = syq * FB_SYC + i;
    #pragma unroll
    for (int n = 0; n < 4; ++n) {
      sum[n] += acc[n];
      const size_t basei = (size_t)NT +
          (((size_t)(b * SY + sy) * CO + m * 16 + kc * 4) * Himg + y) * Wimg +
          x0 + n * 16 + lx;
      #pragma unroll
      for (int j = 0; j < 4; ++j)
        out[basei + (size_t)j * IMG] = acc[n][j];
    }
    __syncthreads();
  }

  #pragma unroll
  for (int n = 0; n < 4; ++n) {
    const size_t baseo =
        ((size_t)(b * CO + m * 16 + kc * 4) * Himg + y) * Wimg + x0 + n * 16 + lx;
    #pragma unroll
    for (int j = 0; j < 4; ++j) {
      const float cyPart = (sum[n][j] - (float)FB_SYC * cx[n][j]) * (1.f / 32.f);
      const float v = cyPart + (syq == 0 ? cx[n][j] : 0.f);
      atomicAdd(&out[baseo + (size_t)j * IMG], v);
    }
  }
}

} // namespace

extern "C" void kernel_launch(void* const* d_in, const int* in_sizes, int n_in,
                              void* d_out, int out_size, void* d_ws, size_t ws_size,
                              hipStream_t stream)
{
  (void)in_sizes; (void)n_in; (void)out_size;
  const float* target  = (const float*)d_in[0];
  const float* support = (const float*)d_in[1];
  const float* Wfull   = (const float*)d_in[2];
  const float* bias    = (const float*)d_in[3];
  float* out = (float*)d_out;

  hipMemsetAsync(d_out, 0, (size_t)NT * sizeof(float), stream);

  if (ws_size >= WS_NEED) {
    unsigned short* ws = (unsigned short*)d_ws;
    transform_nhwc<<<dim3((Bb * SY + Bb) * 64), 256, 0, stream>>>(target, support, ws);
    conv_nhwc2<<<dim3(2048), 256, 0, stream>>>(ws, Wfull, bias, out);
  } else {
    fb_cross_mfma<<<dim3(1024), FB_NTHR, 0, stream>>>(target, support, Wfull, bias, out);
  }
}

// Round 11
// 267.460 us; speedup vs baseline: 1.4595x; 1.2602x over previous
//
#include <hip/hip_runtime.h>

typedef short bf16x8 __attribute__((ext_vector_type(8)));
typedef float f32x4  __attribute__((ext_vector_type(4)));

namespace {

constexpr int CIN = 32, CO = 32, Himg = 128, Wimg = 128, SY = 32, Bb = 4;
constexpr int IMG = Himg * Wimg;                 // 16384
constexpr int NT  = Bb * CO * IMG;               // new_target elems
constexpr size_t IS = (size_t)IMG * CIN;         // 524288 shorts per ws image (1 MB)
// ws image layout: [row y][plane kc(4)][px(128)][ci8] -> row 8192 B, plane 2048 B
constexpr size_t WS_NEED = (size_t)(Bb * SY + Bb) * IS * 2;  // 138,412,032 B

__device__ __forceinline__ unsigned cvtpk(float lo, float hi) {
  unsigned r;
  asm("v_cvt_pk_bf16_f32 %0, %1, %2" : "=v"(r) : "v"(lo), "v"(hi));
  return r;
}

#define GLD16(g, l)                                                        \
  __builtin_amdgcn_global_load_lds(                                       \
      (const __attribute__((address_space(1))) void*)(g),                 \
      (__attribute__((address_space(3))) void*)(l), 16, 0, 0)

#define FENCE() asm volatile("" ::: "memory")
#define BARX()                          \
  do {                                  \
    FENCE();                            \
    __builtin_amdgcn_s_barrier();       \
    FENCE();                            \
    __builtin_amdgcn_sched_barrier(0);  \
  } while (0)
#define WAITV(n) asm volatile("s_waitcnt vmcnt(" #n ")" ::: "memory")

// per-lane A fragments (weights) for one co-tile m; ci = cioff + kc*8 + j
__device__ __forceinline__ void load_w(bf16x8 wf[9],
                                       const float* __restrict__ Wfull,
                                       int cioff, int m, int lane)
{
  const int lx = lane & 15, kc = lane >> 4;
  #pragma unroll
  for (int tap = 0; tap < 9; ++tap) {
    const float* base = Wfull + (size_t)((m * 16 + lx) * 64 + cioff + kc * 8) * 9 + tap;
    bf16x8 w;
    #pragma unroll
    for (int j = 0; j < 8; ++j) {
      unsigned u = __builtin_bit_cast(unsigned, base[j * 9]);
      w[j] = (short)((u + 0x7FFFu + ((u >> 16) & 1u)) >> 16);
    }
    wf[tap] = w;
  }
}

// ================= kernel T: NCHW f32 -> plane-major NHWC bf16 =================
__global__ __launch_bounds__(256)
void transform_nhwc(const float* __restrict__ target,
                    const float* __restrict__ support,
                    unsigned short* __restrict__ ws)
{
  __shared__ unsigned lbuf[256 * 17];

  const int tid   = threadIdx.x;
  const int img   = blockIdx.x >> 6;
  const int chunk = blockIdx.x & 63;
  const float* src = (img < Bb * SY)
      ? support + (size_t)img * CIN * IMG
      : target  + (size_t)(img - Bb * SY) * CIN * IMG;
  const int y0 = chunk * 2;

  // phase R: 1024 tasks = c2(16 ci-pairs) x quad(64 px-quads over 2 rows)
  f32x4 a[4], bv[4];
  #pragma unroll
  for (int k = 0; k < 4; ++k) {
    const int task = tid + k * 256;
    const int c2 = task >> 6, quad = task & 63;
    const float* p = src + (size_t)(2 * c2) * IMG + y0 * Wimg + quad * 4;
    a[k]  = *reinterpret_cast<const f32x4*>(p);
    bv[k] = *reinterpret_cast<const f32x4*>(p + IMG);
  }
  #pragma unroll
  for (int k = 0; k < 4; ++k) {
    const int task = tid + k * 256;
    const int c2 = task >> 6, quad = task & 63;
    #pragma unroll
    for (int e = 0; e < 4; ++e) {
      const int px = quad * 4 + e;   // 0..255 linear over 2 rows
      lbuf[px * 17 + (c2 ^ ((px >> 2) & 15))] = cvtpk(a[k][e], bv[k][e]);
    }
  }
  __syncthreads();

  // phase W: granule G = (r, kc, px); 16B coalesced stores, plane-major rows
  #pragma unroll
  for (int k = 0; k < 4; ++k) {
    const int G = tid + k * 256;            // 0..1023
    const int r  = G >> 9;
    const int kc = (G >> 7) & 3;
    const int px = G & 127;
    const int pl = r * 128 + px;            // linear px over 2 rows
    uint4 v;
    unsigned* vp = reinterpret_cast<unsigned*>(&v);
    #pragma unroll
    for (int w = 0; w < 3 + 1; ++w)
      vp[w] = lbuf[pl * 17 + ((kc * 4 + w) ^ ((pl >> 2) & 15))];
    unsigned short* dst = ws + (size_t)img * IS + (size_t)(y0 + r) * 4096 + kc * 1024 + px * 8;
    *reinterpret_cast<uint4*>(dst) = v;
  }
}

// ================= kernel C: LDS double-buffered DMA conv =================

// stage one image (4 input rows, clamped) into one 32KB LDS buffer
__device__ __forceinline__ void stage_img(char* __restrict__ ldsbuf,
                                          const char* __restrict__ imgbase,
                                          int y, int w, int lane)
{
  #pragma unroll
  for (int j = 0; j < 4; ++j) {
    const int c = w * 4 + j;                 // 0..31 chunks of 1KB
    const int ri = c >> 3, kc4 = (c >> 1) & 3, half = c & 1;
    int sr = y - 1 + ri;
    sr = sr < 0 ? 0 : (sr > 127 ? 127 : sr);
    const char* src = imgbase + (size_t)sr * 8192 + kc4 * 2048 + half * 1024 + lane * 16;
    char* dst = ldsbuf + ri * 8192 + kc4 * 2048 + half * 1024;
    GLD16(src, dst);
  }
}

__device__ __forceinline__ bf16x8 ld_frag(const char* __restrict__ buf,
                                          int ri, int kc, int s)
{
  return *reinterpret_cast<const bf16x8*>(buf + ri * 8192 + kc * 2048 + s * 16);
}

// conv one image from LDS buffer into acc[2 rows][2 n-tiles]
__device__ __forceinline__ void conv_one(f32x4 acc[2][2],
                                         const char* __restrict__ buf,
                                         const bf16x8 wf[9],
                                         int sbase, int kc,
                                         bool rok0, bool rok3)
{
  #pragma unroll
  for (int ri = 0; ri < 4; ++ri) {
    bf16x8 F[6];   // [n*3+kx]
    // n=0,kx=0 : s may be -1 (pxq==0 && lx==0)
    {
      const int s = sbase - 1;
      const int sc = s < 0 ? 0 : s;
      bf16x8 v = ld_frag(buf, ri, kc, sc);
      if (s < 0) v = bf16x8{0, 0, 0, 0, 0, 0, 0, 0};
      F[0] = v;
    }
    F[1] = ld_frag(buf, ri, kc, sbase);
    F[2] = ld_frag(buf, ri, kc, sbase + 1);
    F[3] = ld_frag(buf, ri, kc, sbase + 15);
    F[4] = ld_frag(buf, ri, kc, sbase + 16);
    // n=1,kx=2 : s may be 128 (pxq==3 && lx==15)
    {
      const int s = sbase + 17;
      const int sc = s > 127 ? 127 : s;
      bf16x8 v = ld_frag(buf, ri, kc, sc);
      if (s > 127) v = bf16x8{0, 0, 0, 0, 0, 0, 0, 0};
      F[5] = v;
    }
    const bool u0 = (ri <= 2) && (ri != 0 || rok0);   // out row 0, ky = ri
    const bool u1 = (ri >= 1) && (ri != 3 || rok3);   // out row 1, ky = ri-1
    if (u0) {
      #pragma unroll
      for (int kx = 0; kx < 3; ++kx)
        #pragma unroll
        for (int n = 0; n < 2; ++n)
          acc[0][n] = __builtin_amdgcn_mfma_f32_16x16x32_bf16(wf[ri * 3 + kx], F[n * 3 + kx], acc[0][n], 0, 0, 0);
    }
    if (u1) {
      #pragma unroll
      for (int kx = 0; kx < 3; ++kx)
        #pragma unroll
        for (int n = 0; n < 2; ++n)
          acc[1][n] = __builtin_amdgcn_mfma_f32_16x16x32_bf16(wf[(ri - 1) * 3 + kx], F[n * 3 + kx], acc[1][n], 0, 0, 0);
    }
  }
}

__global__ __launch_bounds__(512, 4)
void conv_lds(const unsigned short* __restrict__ ws,
              const float* __restrict__ Wfull,
              const float* __restrict__ bias,
              float* __restrict__ out)
{
  __shared__ char lds[2 * 32768];

  const int tid = threadIdx.x, lane = tid & 63, w = tid >> 6;
  const int pxq = w & 3, m = w >> 2;
  const int lx = lane & 15, kc = lane >> 4;

  // bijective XCD swizzle over 1024 blocks (1024 % 8 == 0)
  const int orig = blockIdx.x;
  const int eff  = (orig & 7) * 128 + (orig >> 3);
  const int yp  = eff & 63;
  const int syq = (eff >> 6) & 3;
  const int b   = eff >> 8;

  const int y  = yp * 2;
  const bool rok0 = (y > 0), rok3 = (y < 126);
  const int sbase = pxq * 32 + lx;      // base px slot for this lane

  const char* tgt  = (const char*)(ws + (size_t)(Bb * SY + b) * IS);
  const char* sup0 = (const char*)(ws + (size_t)(b * SY + syq * 8) * IS);

  bf16x8 wf[9];
  load_w(wf, Wfull, 0, m, lane);                    // Wx

  // ---- target -> buf0, compute cx ----
  stage_img(lds, tgt, y, w, lane);
  WAITV(0);
  __syncthreads();

  f32x4 cx[2][2];
  #pragma unroll
  for (int r2 = 0; r2 < 2; ++r2)
    #pragma unroll
    for (int n = 0; n < 2; ++n) cx[r2][n] = f32x4{0.f, 0.f, 0.f, 0.f};
  conv_one(cx, lds, wf, sbase, kc, rok0, rok3);
  #pragma unroll
  for (int j = 0; j < 4; ++j) {
    const float bvv = bias[m * 16 + kc * 4 + j];
    #pragma unroll
    for (int r2 = 0; r2 < 2; ++r2)
      #pragma unroll
      for (int n = 0; n < 2; ++n) cx[r2][n][j] += bvv;
  }
  load_w(wf, Wfull, 32, m, lane);                   // Wy

  BARX();                                           // all waves done reading buf0

  // ---- prologue: stage img0 -> buf0, img1 -> buf1 ----
  stage_img(lds,         sup0,                 y, w, lane);
  stage_img(lds + 32768, sup0 + (size_t)IS * 2, y, w, lane);
  WAITV(4);                                         // img0's 4 loads done
  BARX();

  f32x4 sum[2][2];
  #pragma unroll
  for (int r2 = 0; r2 < 2; ++r2)
    #pragma unroll
    for (int n = 0; n < 2; ++n) sum[r2][n] = f32x4{0.f, 0.f, 0.f, 0.f};

  for (int i = 0; i < 8; ++i) {
    const char* cb = lds + (i & 1) * 32768;

    f32x4 acc[2][2];
    #pragma unroll
    for (int r2 = 0; r2 < 2; ++r2)
      #pragma unroll
      for (int n = 0; n < 2; ++n) acc[r2][n] = cx[r2][n];
    conv_one(acc, cb, wf, sbase, kc, rok0, rok3);

    const int sy = syq * 8 + i;
    #pragma unroll
    for (int r2 = 0; r2 < 2; ++r2)
      #pragma unroll
      for (int n = 0; n < 2; ++n) {
        sum[r2][n] += acc[r2][n];
        const size_t basei = (size_t)NT +
            (((size_t)(b * SY + sy) * CO + m * 16 + kc * 4) * Himg + y + r2) * Wimg +
            pxq * 32 + n * 16 + lx;
        #pragma unroll
        for (int j = 0; j < 4; ++j)
          out[basei + (size_t)j * IMG] = acc[r2][n][j];
      }

    BARX();                                         // all waves done reading cb
    if (i + 2 < 8)
      stage_img(lds + (i & 1) * 32768, sup0 + (size_t)(i + 2) * IS * 2, y, w, lane);
    WAITV(4);                                       // img i+1 staged & stores drained
    BARX();
  }

  // ---- new_target partial (4 syq partials per element) ----
  #pragma unroll
  for (int r2 = 0; r2 < 2; ++r2)
    #pragma unroll
    for (int n = 0; n < 2; ++n) {
      const size_t baseo =
          ((size_t)(b * CO + m * 16 + kc * 4) * Himg + y + r2) * Wimg + pxq * 32 + n * 16 + lx;
      #pragma unroll
      for (int j = 0; j < 4; ++j) {
        const float cyPart = (sum[r2][n][j] - 8.f * cx[r2][n][j]) * (1.f / 32.f);
        const float v = cyPart + (syq == 0 ? cx[r2][n][j] : 0.f);
        atomicAdd(&out[baseo + (size_t)j * IMG], v);
      }
    }
}

// ============ fallback (round-4 kernel, used only if ws too small) ============
constexpr int TROWS = 6, TQ = 17, TCOLS = 70;
constexpr int NPIX  = TROWS * TCOLS;
constexpr int LDSB  = NPIX * 64;
constexpr int RTASK = TROWS * TQ;
constexpr int FB_NTHR = 512;
constexpr int FB_TPT  = 4;
constexpr int FB_SYC  = 8;

__device__ __forceinline__ int fb_swz(int pix, int cb) {
  return (pix * 64 + cb) ^ ((pix & 7) << 4);
}
__device__ __forceinline__ void fb_task_decode(int t, int& ch, int& row, int& q, bool& act) {
  ch = t & 15;
  const int r = t >> 4;
  row = r / TQ;
  q   = r - row * TQ;
  act = (r < RTASK);
}
__device__ __forceinline__ void fb_stage_load(f32x4 va[FB_TPT], f32x4 vb[FB_TPT],
                                              const float* __restrict__ src,
                                              int y0, int xq0, int tid)
{
  #pragma unroll
  for (int k = 0; k < FB_TPT; ++k) {
    int ch, row, q; bool act;
    fb_task_decode(tid + k * FB_NTHR, ch, row, q, act);
    const int y = y0 - 1 + row;
    act = act && ((unsigned)y < (unsigned)Himg);
    f32x4 v0 = {0.f, 0.f, 0.f, 0.f}, v1 = {0.f, 0.f, 0.f, 0.f};
    if (act) {
      const float* p = src + (size_t)(2 * ch) * IMG + y * Wimg + 4 * (xq0 + q);
      v0 = *reinterpret_cast<const f32x4*>(p);
      v1 = *reinterpret_cast<const f32x4*>(p + IMG);
    }
    va[k] = v0; vb[k] = v1;
  }
}
__device__ __forceinline__ void fb_stage_write(const f32x4 va[FB_TPT], const f32x4 vb[FB_TPT],
                                               char* __restrict__ lds,
                                               int y0, int xq0, int x0, int tid)
{
  #pragma unroll
  for (int k = 0; k < FB_TPT; ++k) {
    int ch, row, q; bool act;
    fb_task_decode(tid + k * FB_NTHR, ch, row, q, act);
    const int y = y0 - 1 + row;
    act = act && ((unsigned)y < (unsigned)Himg);
    if (act) {
      const int ix0 = 4 * (xq0 + q) - x0 + 1;
      #pragma unroll
      for (int e = 0; e < 4; ++e) {
        const int ix = ix0 + e;
        if (ix >= 0) {
          const int pix = row * TCOLS + ix;
          *reinterpret_cast<unsigned*>(lds + fb_swz(pix, ch * 4)) =
              cvtpk(va[k][e], vb[k][e]);
        }
      }
    }
  }
}
__device__ __forceinline__ void fb_conv1(f32x4 acc[4],
                                         const char* __restrict__ lds,
                                         const bf16x8 wf[9],
                                         int row, int lane)
{
  const int lx = lane & 15, kc = lane >> 4;
  #pragma unroll
  for (int ky = 0; ky < 3; ++ky) {
    #pragma unroll
    for (int kx = 0; kx < 3; ++kx) {
      const int tap = ky * 3 + kx;
      #pragma unroll
      for (int n = 0; n < 4; ++n) {
        const int p = (row + ky) * TCOLS + n * 16 + lx + kx;
        const bf16x8 bfrag = *reinterpret_cast<const bf16x8*>(lds + fb_swz(p, kc * 16));
        acc[n] = __builtin_amdgcn_mfma_f32_16x16x32_bf16(wf[tap], bfrag, acc[n], 0, 0, 0);
      }
    }
  }
}
__global__ __launch_bounds__(FB_NTHR, 4)
void fb_cross_mfma(const float* __restrict__ target,
                   const float* __restrict__ support,
                   const float* __restrict__ Wfull,
                   const float* __restrict__ bias,
                   float* __restrict__ out)
{
  __shared__ char lds[LDSB];
  const int tid  = threadIdx.x;
  const int lane = tid & 63;
  const int wv   = tid >> 6;
  const int row  = wv & 3;
  const int m    = wv >> 2;
  const int lx = lane & 15, kc = lane >> 4;
  const int bid = blockIdx.x;
  const int syq = bid & 3;
  const int xh  = (bid >> 2) & 1;
  const int yb  = (bid >> 3) & 31;
  const int b   = bid >> 8;
  const int y0 = yb * 4, x0 = xh * 64;
  const int y  = y0 + row;
  const int xq0 = xh ? 15 : 0;

  for (int e = tid; e < NPIX * 4; e += FB_NTHR)
    reinterpret_cast<f32x4*>(lds)[e] = f32x4{0.f, 0.f, 0.f, 0.f};

  bf16x8 wf[9];
  load_w(wf, Wfull, 0, m, lane);
  f32x4 va[FB_TPT], vb[FB_TPT];
  fb_stage_load(va, vb, target + (size_t)b * CIN * IMG, y0, xq0, tid);
  __syncthreads();
  fb_stage_write(va, vb, lds, y0, xq0, x0, tid);
  __syncthreads();

  f32x4 cx[4];
  #pragma unroll
  for (int n = 0; n < 4; ++n) cx[n] = f32x4{0.f, 0.f, 0.f, 0.f};
  fb_conv1(cx, lds, wf, row, lane);
  #pragma unroll
  for (int j = 0; j < 4; ++j) {
    const float bvv = bias[m * 16 + kc * 4 + j];
    #pragma unroll
    for (int n = 0; n < 4; ++n) cx[n][j] += bvv;
  }

  const float* supp0 = support + (size_t)(b * SY + syq * FB_SYC) * CIN * IMG;
  fb_stage_load(va, vb, supp0, y0, xq0, tid);
  load_w(wf, Wfull, 32, m, lane);
  __syncthreads();
  fb_stage_write(va, vb, lds, y0, xq0, x0, tid);

  f32x4 sum[4];
  #pragma unroll
  for (int n = 0; n < 4; ++n) sum[n] = f32x4{0.f, 0.f, 0.f, 0.f};
  __syncthreads();

  for (int i = 0; i < FB_SYC; ++i) {
    if (i < FB_SYC - 1)
      fb_stage_load(va, vb, supp0 + (size_t)(i + 1) * CIN * IMG, y0, xq0, tid);

    f32x4 acc[4];
    #pragma unroll
    for (int n = 0; n < 4; ++n) acc[n] = cx[n];
    fb_conv1(acc, lds, wf, row, lane);
    __syncthreads();

    if (i < FB_SYC - 1)
      fb_stage_write(va, vb, lds, y0, xq0, x0, tid);

    const int sy = syq * FB_SYC + i;
    #pragma unroll
    for (int n = 0; n < 4; ++n) {
      sum[n] += acc[n];
      const size_t basei = (size_t)NT +
          (((size_t)(b * SY + sy) * CO + m * 16 + kc * 4) * Himg + y) * Wimg +
          x0 + n * 16 + lx;
      #pragma unroll
      for (int j = 0; j < 4; ++j)
        out[basei + (size_t)j * IMG] = acc[n][j];
    }
    __syncthreads();
  }

  #pragma unroll
  for (int n = 0; n < 4; ++n) {
    const size_t baseo =
        ((size_t)(b * CO + m * 16 + kc * 4) * Himg + y) * Wimg + x0 + n * 16 + lx;
    #pragma unroll
    for (int j = 0; j < 4; ++j) {
      const float cyPart = (sum[n][j] - (float)FB_SYC * cx[n][j]) * (1.f / 32.f);
      const float v = cyPart + (syq == 0 ? cx[n][j] : 0.f);
      atomicAdd(&out[baseo + (size_t)j * IMG], v);
    }
  }
}

} // namespace

extern "C" void kernel_launch(void* const* d_in, const int* in_sizes, int n_in,
                              void* d_out, int out_size, void* d_ws, size_t ws_size,
                              hipStream_t stream)
{
  (void)in_sizes; (void)n_in; (void)out_size;
  const float* target  = (const float*)d_in[0];
  const float* support = (const float*)d_in[1];
  const float* Wfull   = (const float*)d_in[2];
  const float* bias    = (const float*)d_in[3];
  float* out = (float*)d_out;

  hipMemsetAsync(d_out, 0, (size_t)NT * sizeof(float), stream);

  if (ws_size >= WS_NEED) {
    unsigned short* ws = (unsigned short*)d_ws;
    transform_nhwc<<<dim3((Bb * SY + Bb) * 64), 256, 0, stream>>>(target, support, ws);
    conv_lds<<<dim3(1024), 512, 0, stream>>>(ws, Wfull, bias, out);
  } else {
    fb_cross_mfma<<<dim3(1024), FB_NTHR, 0, stream>>>(target, support, Wfull, bias, out);
  }
}

// Round 12
// 244.597 us; speedup vs baseline: 1.5959x; 1.0935x over previous
//
#include <hip/hip_runtime.h>

typedef short bf16x8 __attribute__((ext_vector_type(8)));
typedef float f32x4  __attribute__((ext_vector_type(4)));

namespace {

constexpr int CIN = 32, CO = 32, Himg = 128, Wimg = 128, SY = 32, Bb = 4;
constexpr int IMG = Himg * Wimg;                 // 16384
constexpr int NT  = Bb * CO * IMG;               // new_target elems
constexpr size_t IS = (size_t)IMG * CIN;         // 524288 shorts per ws image (1 MB)
// ws layout: img 0..127 = support, 128..131 = target, 132..135 = mean(support) per b
// image layout: [row y][plane kc(4)][px(128)][ci8] -> row 8192 B, plane 2048 B
constexpr size_t WS1 = (size_t)132 * IS * 2;     // 138,412,032 B (no-mean path)
constexpr size_t WS2 = (size_t)136 * IS * 2;     // 142,606,336 B (mean path)

__device__ __forceinline__ unsigned cvtpk(float lo, float hi) {
  unsigned r;
  asm("v_cvt_pk_bf16_f32 %0, %1, %2" : "=v"(r) : "v"(lo), "v"(hi));
  return r;
}

#define GLD16(g, l)                                                        \
  __builtin_amdgcn_global_load_lds(                                       \
      (const __attribute__((address_space(1))) void*)(g),                 \
      (__attribute__((address_space(3))) void*)(l), 16, 0, 0)

#define FENCE() asm volatile("" ::: "memory")
#define BARX()                          \
  do {                                  \
    FENCE();                            \
    __builtin_amdgcn_s_barrier();       \
    FENCE();                            \
    __builtin_amdgcn_sched_barrier(0);  \
  } while (0)
#define WAITV(n) asm volatile("s_waitcnt vmcnt(" #n ")" ::: "memory")

// per-lane A fragments (weights) for one co-tile m; ci = cioff + kc*8 + j
__device__ __forceinline__ void load_w(bf16x8 wf[9],
                                       const float* __restrict__ Wfull,
                                       int cioff, int m, int lane)
{
  const int lx = lane & 15, kc = lane >> 4;
  #pragma unroll
  for (int tap = 0; tap < 9; ++tap) {
    const float* base = Wfull + (size_t)((m * 16 + lx) * 64 + cioff + kc * 8) * 9 + tap;
    bf16x8 w;
    #pragma unroll
    for (int j = 0; j < 8; ++j) {
      unsigned u = __builtin_bit_cast(unsigned, base[j * 9]);
      w[j] = (short)((u + 0x7FFFu + ((u >> 16) & 1u)) >> 16);
    }
    wf[tap] = w;
  }
}

// ================= kernel T: NCHW f32 -> plane-major NHWC bf16 =================
__global__ __launch_bounds__(256)
void transform_nhwc(const float* __restrict__ target,
                    const float* __restrict__ support,
                    unsigned short* __restrict__ ws)
{
  __shared__ unsigned lbuf[256 * 17];

  const int tid   = threadIdx.x;
  const int img   = blockIdx.x >> 6;
  const int chunk = blockIdx.x & 63;
  const float* src = (img < Bb * SY)
      ? support + (size_t)img * CIN * IMG
      : target  + (size_t)(img - Bb * SY) * CIN * IMG;
  const int y0 = chunk * 2;

  f32x4 a[4], bv[4];
  #pragma unroll
  for (int k = 0; k < 4; ++k) {
    const int task = tid + k * 256;
    const int c2 = task >> 6, quad = task & 63;
    const float* p = src + (size_t)(2 * c2) * IMG + y0 * Wimg + quad * 4;
    a[k]  = *reinterpret_cast<const f32x4*>(p);
    bv[k] = *reinterpret_cast<const f32x4*>(p + IMG);
  }
  #pragma unroll
  for (int k = 0; k < 4; ++k) {
    const int task = tid + k * 256;
    const int c2 = task >> 6, quad = task & 63;
    #pragma unroll
    for (int e = 0; e < 4; ++e) {
      const int px = quad * 4 + e;   // 0..255 linear over 2 rows
      lbuf[px * 17 + (c2 ^ ((px >> 2) & 15))] = cvtpk(a[k][e], bv[k][e]);
    }
  }
  __syncthreads();

  #pragma unroll
  for (int k = 0; k < 4; ++k) {
    const int G = tid + k * 256;            // 0..1023
    const int r  = G >> 9;
    const int kc = (G >> 7) & 3;
    const int px = G & 127;
    const int pl = r * 128 + px;
    uint4 v;
    unsigned* vp = reinterpret_cast<unsigned*>(&v);
    #pragma unroll
    for (int w = 0; w < 4; ++w)
      vp[w] = lbuf[pl * 17 + ((kc * 4 + w) ^ ((pl >> 2) & 15))];
    unsigned short* dst = ws + (size_t)img * IS + (size_t)(y0 + r) * 4096 + kc * 1024 + px * 8;
    *reinterpret_cast<uint4*>(dst) = v;
  }
}

// ============ kernel M: mean over sy of ws support (bf16, elementwise) ============
__global__ __launch_bounds__(256)
void mean_k(unsigned short* __restrict__ ws)
{
  const int b = blockIdx.x >> 7, y = blockIdx.x & 127;
  const size_t off = (size_t)y * 4096 + threadIdx.x * 16;   // 16 shorts per thread

  float s[16];
  #pragma unroll
  for (int k = 0; k < 16; ++k) s[k] = 0.f;

  #pragma unroll 4
  for (int sy = 0; sy < SY; ++sy) {
    const uint4* p = reinterpret_cast<const uint4*>(ws + (size_t)(b * SY + sy) * IS + off);
    uint4 v0 = p[0], v1 = p[1];
    const unsigned* w0 = reinterpret_cast<const unsigned*>(&v0);
    const unsigned* w1 = reinterpret_cast<const unsigned*>(&v1);
    #pragma unroll
    for (int q = 0; q < 4; ++q) {
      s[2 * q + 0] += __builtin_bit_cast(float, w0[q] << 16);
      s[2 * q + 1] += __builtin_bit_cast(float, w0[q] & 0xffff0000u);
      s[8 + 2 * q + 0] += __builtin_bit_cast(float, w1[q] << 16);
      s[8 + 2 * q + 1] += __builtin_bit_cast(float, w1[q] & 0xffff0000u);
    }
  }

  constexpr float inv = 1.0f / SY;
  uint4 o0, o1;
  unsigned* q0 = reinterpret_cast<unsigned*>(&o0);
  unsigned* q1 = reinterpret_cast<unsigned*>(&o1);
  #pragma unroll
  for (int q = 0; q < 4; ++q) {
    q0[q] = cvtpk(s[2 * q] * inv, s[2 * q + 1] * inv);
    q1[q] = cvtpk(s[8 + 2 * q] * inv, s[8 + 2 * q + 1] * inv);
  }
  uint4* dst = reinterpret_cast<uint4*>(ws + (size_t)(132 + b) * IS + off);
  dst[0] = o0;
  dst[1] = o1;
}

// ================= kernel C: LDS double-buffered DMA conv =================

// stage one image (4 input rows, clamped) into one 32KB LDS buffer
__device__ __forceinline__ void stage_img(char* __restrict__ ldsbuf,
                                          const char* __restrict__ imgbase,
                                          int y, int w, int lane)
{
  #pragma unroll
  for (int j = 0; j < 4; ++j) {
    const int c = w * 4 + j;                 // 0..31 chunks of 1KB
    const int ri = c >> 3, kc4 = (c >> 1) & 3, half = c & 1;
    int sr = y - 1 + ri;
    sr = sr < 0 ? 0 : (sr > 127 ? 127 : sr);
    const char* src = imgbase + (size_t)sr * 8192 + kc4 * 2048 + half * 1024 + lane * 16;
    char* dst = ldsbuf + ri * 8192 + kc4 * 2048 + half * 1024;
    GLD16(src, dst);
  }
}

__device__ __forceinline__ bf16x8 ld_frag(const char* __restrict__ buf,
                                          int ri, int kc, int s)
{
  return *reinterpret_cast<const bf16x8*>(buf + ri * 8192 + kc * 2048 + s * 16);
}

// conv one image from LDS buffer into acc[2 rows][2 n-tiles]
__device__ __forceinline__ void conv_one(f32x4 acc[2][2],
                                         const char* __restrict__ buf,
                                         const bf16x8 wf[9],
                                         int sbase, int kc,
                                         bool rok0, bool rok3)
{
  #pragma unroll
  for (int ri = 0; ri < 4; ++ri) {
    bf16x8 F[6];   // [n*3+kx]
    {
      const int s = sbase - 1;
      const int sc = s < 0 ? 0 : s;
      bf16x8 v = ld_frag(buf, ri, kc, sc);
      if (s < 0) v = bf16x8{0, 0, 0, 0, 0, 0, 0, 0};
      F[0] = v;
    }
    F[1] = ld_frag(buf, ri, kc, sbase);
    F[2] = ld_frag(buf, ri, kc, sbase + 1);
    F[3] = ld_frag(buf, ri, kc, sbase + 15);
    F[4] = ld_frag(buf, ri, kc, sbase + 16);
    {
      const int s = sbase + 17;
      const int sc = s > 127 ? 127 : s;
      bf16x8 v = ld_frag(buf, ri, kc, sc);
      if (s > 127) v = bf16x8{0, 0, 0, 0, 0, 0, 0, 0};
      F[5] = v;
    }
    const bool u0 = (ri <= 2) && (ri != 0 || rok0);   // out row 0, ky = ri
    const bool u1 = (ri >= 1) && (ri != 3 || rok3);   // out row 1, ky = ri-1
    if (u0) {
      #pragma unroll
      for (int kx = 0; kx < 3; ++kx)
        #pragma unroll
        for (int n = 0; n < 2; ++n)
          acc[0][n] = __builtin_amdgcn_mfma_f32_16x16x32_bf16(wf[ri * 3 + kx], F[n * 3 + kx], acc[0][n], 0, 0, 0);
    }
    if (u1) {
      #pragma unroll
      for (int kx = 0; kx < 3; ++kx)
        #pragma unroll
        for (int n = 0; n < 2; ++n)
          acc[1][n] = __builtin_amdgcn_mfma_f32_16x16x32_bf16(wf[(ri - 1) * 3 + kx], F[n * 3 + kx], acc[1][n], 0, 0, 0);
    }
  }
}

template <bool NTMEAN>
__global__ __launch_bounds__(512, 4)
void conv_lds(const unsigned short* __restrict__ ws,
              const float* __restrict__ Wfull,
              const float* __restrict__ bias,
              float* __restrict__ out)
{
  __shared__ char lds[2 * 32768];

  const int tid = threadIdx.x, lane = tid & 63, w = tid >> 6;
  const int pxq = w & 3, m = w >> 2;
  const int lx = lane & 15, kc = lane >> 4;

  // bijective XCD swizzle over 1024 blocks (1024 % 8 == 0)
  const int orig = blockIdx.x;
  const int eff  = (orig & 7) * 128 + (orig >> 3);
  const int yp  = eff & 63;
  const int syq = (eff >> 6) & 3;
  const int b   = eff >> 8;

  const int y  = yp * 2;
  const bool rok0 = (y > 0), rok3 = (y < 126);
  const int sbase = pxq * 32 + lx;      // base px slot for this lane

  const char* tgt  = (const char*)(ws + (size_t)(Bb * SY + b) * IS);
  const char* sup0 = (const char*)(ws + (size_t)(b * SY + syq * 8) * IS);
  const char* mnp  = (const char*)(ws + (size_t)(132 + b) * IS);

  // this block also computes new_target rows (balanced across syq)
  const bool doNT = NTMEAN && (syq == (yp & 3));
  const int nimg = doNT ? 9 : 8;        // image 8 == mean image

  bf16x8 wf[9];
  load_w(wf, Wfull, 0, m, lane);                    // Wx

  // ---- target -> buf0, compute cx (= conv_Wx(target) + bias) ----
  stage_img(lds, tgt, y, w, lane);
  WAITV(0);
  __syncthreads();

  f32x4 cx[2][2];
  #pragma unroll
  for (int r2 = 0; r2 < 2; ++r2)
    #pragma unroll
    for (int n = 0; n < 2; ++n) cx[r2][n] = f32x4{0.f, 0.f, 0.f, 0.f};
  conv_one(cx, lds, wf, sbase, kc, rok0, rok3);
  #pragma unroll
  for (int j = 0; j < 4; ++j) {
    const float bvv = bias[m * 16 + kc * 4 + j];
    #pragma unroll
    for (int r2 = 0; r2 < 2; ++r2)
      #pragma unroll
      for (int n = 0; n < 2; ++n) cx[r2][n][j] += bvv;
  }
  load_w(wf, Wfull, 32, m, lane);                   // Wy

  BARX();                                           // all waves done reading buf0

  // ---- prologue: stage img0 -> buf0, img1 -> buf1 ----
  stage_img(lds,         sup0,                  y, w, lane);
  stage_img(lds + 32768, sup0 + (size_t)IS * 2, y, w, lane);
  WAITV(4);                                         // img0's 4 loads done
  BARX();

  f32x4 sum[2][2];
  if constexpr (!NTMEAN) {
    #pragma unroll
    for (int r2 = 0; r2 < 2; ++r2)
      #pragma unroll
      for (int n = 0; n < 2; ++n) sum[r2][n] = f32x4{0.f, 0.f, 0.f, 0.f};
  }

  for (int i = 0; i < nimg; ++i) {
    const char* cb = lds + (i & 1) * 32768;

    f32x4 acc[2][2];
    #pragma unroll
    for (int r2 = 0; r2 < 2; ++r2)
      #pragma unroll
      for (int n = 0; n < 2; ++n) acc[r2][n] = cx[r2][n];
    conv_one(acc, cb, wf, sbase, kc, rok0, rok3);

    if (!NTMEAN || i < 8) {
      const int sy = syq * 8 + i;
      #pragma unroll
      for (int r2 = 0; r2 < 2; ++r2)
        #pragma unroll
        for (int n = 0; n < 2; ++n) {
          if constexpr (!NTMEAN) sum[r2][n] += acc[r2][n];
          const size_t basei = (size_t)NT +
              (((size_t)(b * SY + sy) * CO + m * 16 + kc * 4) * Himg + y + r2) * Wimg +
              pxq * 32 + n * 16 + lx;
          #pragma unroll
          for (int j = 0; j < 4; ++j)
            out[basei + (size_t)j * IMG] = acc[r2][n][j];
        }
    } else {
      // mean image: acc = cx + bias + conv_Wy(mean) == new_target rows
      #pragma unroll
      for (int r2 = 0; r2 < 2; ++r2)
        #pragma unroll
        for (int n = 0; n < 2; ++n) {
          const size_t baseo =
              ((size_t)(b * CO + m * 16 + kc * 4) * Himg + y + r2) * Wimg +
              pxq * 32 + n * 16 + lx;
          #pragma unroll
          for (int j = 0; j < 4; ++j)
            out[baseo + (size_t)j * IMG] = acc[r2][n][j];
        }
    }

    BARX();                                         // all waves done reading cb
    if (i + 2 < nimg) {
      const char* nsrc = (i + 2 < 8) ? sup0 + (size_t)(i + 2) * IS * 2 : mnp;
      stage_img(lds + (i & 1) * 32768, nsrc, y, w, lane);
    }
    WAITV(4);                                       // img i+1 staged
    BARX();
  }

  if constexpr (!NTMEAN) {
    // new_target partial (4 syq partials per element)
    #pragma unroll
    for (int r2 = 0; r2 < 2; ++r2)
      #pragma unroll
      for (int n = 0; n < 2; ++n) {
        const size_t baseo =
            ((size_t)(b * CO + m * 16 + kc * 4) * Himg + y + r2) * Wimg + pxq * 32 + n * 16 + lx;
        #pragma unroll
        for (int j = 0; j < 4; ++j) {
          const float cyPart = (sum[r2][n][j] - 8.f * cx[r2][n][j]) * (1.f / 32.f);
          const float v = cyPart + (syq == 0 ? cx[r2][n][j] : 0.f);
          atomicAdd(&out[baseo + (size_t)j * IMG], v);
        }
      }
  }
}

// ============ fallback (round-4 kernel, used only if ws too small) ============
constexpr int TROWS = 6, TQ = 17, TCOLS = 70;
constexpr int NPIX  = TROWS * TCOLS;
constexpr int LDSB  = NPIX * 64;
constexpr int RTASK = TROWS * TQ;
constexpr int FB_NTHR = 512;
constexpr int FB_TPT  = 4;
constexpr int FB_SYC  = 8;

__device__ __forceinline__ int fb_swz(int pix, int cb) {
  return (pix * 64 + cb) ^ ((pix & 7) << 4);
}
__device__ __forceinline__ void fb_task_decode(int t, int& ch, int& row, int& q, bool& act) {
  ch = t & 15;
  const int r = t >> 4;
  row = r / TQ;
  q   = r - row * TQ;
  act = (r < RTASK);
}
__device__ __forceinline__ void fb_stage_load(f32x4 va[FB_TPT], f32x4 vb[FB_TPT],
                                              const float* __restrict__ src,
                                              int y0, int xq0, int tid)
{
  #pragma unroll
  for (int k = 0; k < FB_TPT; ++k) {
    int ch, row, q; bool act;
    fb_task_decode(tid + k * FB_NTHR, ch, row, q, act);
    const int y = y0 - 1 + row;
    act = act && ((unsigned)y < (unsigned)Himg);
    f32x4 v0 = {0.f, 0.f, 0.f, 0.f}, v1 = {0.f, 0.f, 0.f, 0.f};
    if (act) {
      const float* p = src + (size_t)(2 * ch) * IMG + y * Wimg + 4 * (xq0 + q);
      v0 = *reinterpret_cast<const f32x4*>(p);
      v1 = *reinterpret_cast<const f32x4*>(p + IMG);
    }
    va[k] = v0; vb[k] = v1;
  }
}
__device__ __forceinline__ void fb_stage_write(const f32x4 va[FB_TPT], const f32x4 vb[FB_TPT],
                                               char* __restrict__ lds,
                                               int y0, int xq0, int x0, int tid)
{
  #pragma unroll
  for (int k = 0; k < FB_TPT; ++k) {
    int ch, row, q; bool act;
    fb_task_decode(tid + k * FB_NTHR, ch, row, q, act);
    const int y = y0 - 1 + row;
    act = act && ((unsigned)y < (unsigned)Himg);
    if (act) {
      const int ix0 = 4 * (xq0 + q) - x0 + 1;
      #pragma unroll
      for (int e = 0; e < 4; ++e) {
        const int ix = ix0 + e;
        if (ix >= 0) {
          const int pix = row * TCOLS + ix;
          *reinterpret_cast<unsigned*>(lds + fb_swz(pix, ch * 4)) =
              cvtpk(va[k][e], vb[k][e]);
        }
      }
    }
  }
}
__device__ __forceinline__ void fb_conv1(f32x4 acc[4],
                                         const char* __restrict__ lds,
                                         const bf16x8 wf[9],
                                         int row, int lane)
{
  const int lx = lane & 15, kc = lane >> 4;
  #pragma unroll
  for (int ky = 0; ky < 3; ++ky) {
    #pragma unroll
    for (int kx = 0; kx < 3; ++kx) {
      const int tap = ky * 3 + kx;
      #pragma unroll
      for (int n = 0; n < 4; ++n) {
        const int p = (row + ky) * TCOLS + n * 16 + lx + kx;
        const bf16x8 bfrag = *reinterpret_cast<const bf16x8*>(lds + fb_swz(p, kc * 16));
        acc[n] = __builtin_amdgcn_mfma_f32_16x16x32_bf16(wf[tap], bfrag, acc[n], 0, 0, 0);
      }
    }
  }
}
__global__ __launch_bounds__(FB_NTHR, 4)
void fb_cross_mfma(const float* __restrict__ target,
                   const float* __restrict__ support,
                   const float* __restrict__ Wfull,
                   const float* __restrict__ bias,
                   float* __restrict__ out)
{
  __shared__ char lds[LDSB];
  const int tid  = threadIdx.x;
  const int lane = tid & 63;
  const int wv   = tid >> 6;
  const int row  = wv & 3;
  const int m    = wv >> 2;
  const int lx = lane & 15, kc = lane >> 4;
  const int bid = blockIdx.x;
  const int syq = bid & 3;
  const int xh  = (bid >> 2) & 1;
  const int yb  = (bid >> 3) & 31;
  const int b   = bid >> 8;
  const int y0 = yb * 4, x0 = xh * 64;
  const int y  = y0 + row;
  const int xq0 = xh ? 15 : 0;

  for (int e = tid; e < NPIX * 4; e += FB_NTHR)
    reinterpret_cast<f32x4*>(lds)[e] = f32x4{0.f, 0.f, 0.f, 0.f};

  bf16x8 wf[9];
  load_w(wf, Wfull, 0, m, lane);
  f32x4 va[FB_TPT], vb[FB_TPT];
  fb_stage_load(va, vb, target + (size_t)b * CIN * IMG, y0, xq0, tid);
  __syncthreads();
  fb_stage_write(va, vb, lds, y0, xq0, x0, tid);
  __syncthreads();

  f32x4 cx[4];
  #pragma unroll
  for (int n = 0; n < 4; ++n) cx[n] = f32x4{0.f, 0.f, 0.f, 0.f};
  fb_conv1(cx, lds, wf, row, lane);
  #pragma unroll
  for (int j = 0; j < 4; ++j) {
    const float bvv = bias[m * 16 + kc * 4 + j];
    #pragma unroll
    for (int n = 0; n < 4; ++n) cx[n][j] += bvv;
  }

  const float* supp0 = support + (size_t)(b * SY + syq * FB_SYC) * CIN * IMG;
  fb_stage_load(va, vb, supp0, y0, xq0, tid);
  load_w(wf, Wfull, 32, m, lane);
  __syncthreads();
  fb_stage_write(va, vb, lds, y0, xq0, x0, tid);

  f32x4 sum[4];
  #pragma unroll
  for (int n = 0; n < 4; ++n) sum[n] = f32x4{0.f, 0.f, 0.f, 0.f};
  __syncthreads();

  for (int i = 0; i < FB_SYC; ++i) {
    if (i < FB_SYC - 1)
      fb_stage_load(va, vb, supp0 + (size_t)(i + 1) * CIN * IMG, y0, xq0, tid);

    f32x4 acc[4];
    #pragma unroll
    for (int n = 0; n < 4; ++n) acc[n] = cx[n];
    fb_conv1(acc, lds, wf, row, lane);
    __syncthreads();

    if (i < FB_SYC - 1)
      fb_stage_write(va, vb, lds, y0, xq0, x0, tid);

    const int sy = syq * FB_SYC + i;
    #pragma unroll
    for (int n = 0; n < 4; ++n) {
      sum[n] += acc[n];
      const size_t basei = (size_t)NT +
          (((size_t)(b * SY + sy) * CO + m * 16 + kc * 4) * Himg + y) * Wimg +
          x0 + n * 16 + lx;
      #pragma unroll
      for (int j = 0; j < 4; ++j)
        out[basei + (size_t)j * IMG] = acc[n][j];
    }
    __syncthreads();
  }

  #pragma unroll
  for (int n = 0; n < 4; ++n) {
    const size_t baseo =
        ((size_t)(b * CO + m * 16 + kc * 4) * Himg + y) * Wimg + x0 + n * 16 + lx;
    #pragma unroll
    for (int j = 0; j < 4; ++j) {
      const float cyPart = (sum[n][j] - (float)FB_SYC * cx[n][j]) * (1.f / 32.f);
      const float v = cyPart + (syq == 0 ? cx[n][j] : 0.f);
      atomicAdd(&out[baseo + (size_t)j * IMG], v);
    }
  }
}

} // namespace

extern "C" void kernel_launch(void* const* d_in, const int* in_sizes, int n_in,
                              void* d_out, int out_size, void* d_ws, size_t ws_size,
                              hipStream_t stream)
{
  (void)in_sizes; (void)n_in; (void)out_size;
  const float* target  = (const float*)d_in[0];
  const float* support = (const float*)d_in[1];
  const float* Wfull   = (const float*)d_in[2];
  const float* bias    = (const float*)d_in[3];
  float* out = (float*)d_out;

  if (ws_size >= WS2) {
    // mean path: every output element written exactly once -> no memset, no atomics
    unsigned short* ws = (unsigned short*)d_ws;
    transform_nhwc<<<dim3((Bb * SY + Bb) * 64), 256, 0, stream>>>(target, support, ws);
    mean_k<<<dim3(512), 256, 0, stream>>>(ws);
    conv_lds<true><<<dim3(1024), 512, 0, stream>>>(ws, Wfull, bias, out);
  } else if (ws_size >= WS1) {
    unsigned short* ws = (unsigned short*)d_ws;
    hipMemsetAsync(d_out, 0, (size_t)NT * sizeof(float), stream);
    transform_nhwc<<<dim3((Bb * SY + Bb) * 64), 256, 0, stream>>>(target, support, ws);
    conv_lds<false><<<dim3(1024), 512, 0, stream>>>(ws, Wfull, bias, out);
  } else {
    hipMemsetAsync(d_out, 0, (size_t)NT * sizeof(float), stream);
    fb_cross_mfma<<<dim3(1024), FB_NTHR, 0, stream>>>(target, support, Wfull, bias, out);
  }
}

// Round 13
// 239.748 us; speedup vs baseline: 1.6282x; 1.0202x over previous
//
#include <hip/hip_runtime.h>

typedef short bf16x8 __attribute__((ext_vector_type(8)));
typedef float f32x4  __attribute__((ext_vector_type(4)));

namespace {

constexpr int CIN = 32, CO = 32, Himg = 128, Wimg = 128, SY = 32, Bb = 4;
constexpr int IMG = Himg * Wimg;                 // 16384
constexpr int NT  = Bb * CO * IMG;               // new_target elems
constexpr size_t IS = (size_t)IMG * CIN;         // 524288 shorts per ws image (1 MB)
// ws layout: img 0..127 = support, 128..131 = target, 132..135 = mean(support) per b
// image layout: [row y][plane kc(4)][px(128)][ci8] -> row 8192 B, plane 2048 B
constexpr size_t WS1 = (size_t)132 * IS * 2;     // 138,412,032 B (no-mean path)
constexpr size_t WS2 = (size_t)136 * IS * 2;     // 142,606,336 B (mean path)

__device__ __forceinline__ unsigned cvtpk(float lo, float hi) {
  unsigned r;
  asm("v_cvt_pk_bf16_f32 %0, %1, %2" : "=v"(r) : "v"(lo), "v"(hi));
  return r;
}

#define GLD16(g, l)                                                        \
  __builtin_amdgcn_global_load_lds(                                       \
      (const __attribute__((address_space(1))) void*)(g),                 \
      (__attribute__((address_space(3))) void*)(l), 16, 0, 0)

#define FENCE() asm volatile("" ::: "memory")
#define BARX()                          \
  do {                                  \
    FENCE();                            \
    __builtin_amdgcn_s_barrier();       \
    FENCE();                            \
    __builtin_amdgcn_sched_barrier(0);  \
  } while (0)
#define WAITV(n) asm volatile("s_waitcnt vmcnt(" #n ")" ::: "memory")

// per-lane A fragments (weights) for one co-tile m; ci = cioff + kc*8 + j
__device__ __forceinline__ void load_w(bf16x8 wf[9],
                                       const float* __restrict__ Wfull,
                                       int cioff, int m, int lane)
{
  const int lx = lane & 15, kc = lane >> 4;
  #pragma unroll
  for (int tap = 0; tap < 9; ++tap) {
    const float* base = Wfull + (size_t)((m * 16 + lx) * 64 + cioff + kc * 8) * 9 + tap;
    bf16x8 w;
    #pragma unroll
    for (int j = 0; j < 8; ++j) {
      unsigned u = __builtin_bit_cast(unsigned, base[j * 9]);
      w[j] = (short)((u + 0x7FFFu + ((u >> 16) & 1u)) >> 16);
    }
    wf[tap] = w;
  }
}

// ================= kernel T: NCHW f32 -> plane-major NHWC bf16 =================
__global__ __launch_bounds__(256)
void transform_nhwc(const float* __restrict__ target,
                    const float* __restrict__ support,
                    unsigned short* __restrict__ ws)
{
  __shared__ unsigned lbuf[256 * 17];

  const int tid   = threadIdx.x;
  const int img   = blockIdx.x >> 6;
  const int chunk = blockIdx.x & 63;
  const float* src = (img < Bb * SY)
      ? support + (size_t)img * CIN * IMG
      : target  + (size_t)(img - Bb * SY) * CIN * IMG;
  const int y0 = chunk * 2;

  f32x4 a[4], bv[4];
  #pragma unroll
  for (int k = 0; k < 4; ++k) {
    const int task = tid + k * 256;
    const int c2 = task >> 6, quad = task & 63;
    const float* p = src + (size_t)(2 * c2) * IMG + y0 * Wimg + quad * 4;
    a[k]  = *reinterpret_cast<const f32x4*>(p);
    bv[k] = *reinterpret_cast<const f32x4*>(p + IMG);
  }
  #pragma unroll
  for (int k = 0; k < 4; ++k) {
    const int task = tid + k * 256;
    const int c2 = task >> 6, quad = task & 63;
    #pragma unroll
    for (int e = 0; e < 4; ++e) {
      const int px = quad * 4 + e;   // 0..255 linear over 2 rows
      lbuf[px * 17 + (c2 ^ ((px >> 2) & 15))] = cvtpk(a[k][e], bv[k][e]);
    }
  }
  __syncthreads();

  #pragma unroll
  for (int k = 0; k < 4; ++k) {
    const int G = tid + k * 256;            // 0..1023
    const int r  = G >> 9;
    const int kc = (G >> 7) & 3;
    const int px = G & 127;
    const int pl = r * 128 + px;
    uint4 v;
    unsigned* vp = reinterpret_cast<unsigned*>(&v);
    #pragma unroll
    for (int w = 0; w < 4; ++w)
      vp[w] = lbuf[pl * 17 + ((kc * 4 + w) ^ ((pl >> 2) & 15))];
    unsigned short* dst = ws + (size_t)img * IS + (size_t)(y0 + r) * 4096 + kc * 1024 + px * 8;
    *reinterpret_cast<uint4*>(dst) = v;
  }
}

// ============ kernel M: mean over sy of ws support (bf16, elementwise) ============
__global__ __launch_bounds__(256)
void mean_k(unsigned short* __restrict__ ws)
{
  const int b = blockIdx.x >> 7, y = blockIdx.x & 127;
  const size_t off = (size_t)y * 4096 + threadIdx.x * 16;   // 16 shorts per thread

  float s[16];
  #pragma unroll
  for (int k = 0; k < 16; ++k) s[k] = 0.f;

  #pragma unroll 4
  for (int sy = 0; sy < SY; ++sy) {
    const uint4* p = reinterpret_cast<const uint4*>(ws + (size_t)(b * SY + sy) * IS + off);
    uint4 v0 = p[0], v1 = p[1];
    const unsigned* w0 = reinterpret_cast<const unsigned*>(&v0);
    const unsigned* w1 = reinterpret_cast<const unsigned*>(&v1);
    #pragma unroll
    for (int q = 0; q < 4; ++q) {
      s[2 * q + 0] += __builtin_bit_cast(float, w0[q] << 16);
      s[2 * q + 1] += __builtin_bit_cast(float, w0[q] & 0xffff0000u);
      s[8 + 2 * q + 0] += __builtin_bit_cast(float, w1[q] << 16);
      s[8 + 2 * q + 1] += __builtin_bit_cast(float, w1[q] & 0xffff0000u);
    }
  }

  constexpr float inv = 1.0f / SY;
  uint4 o0, o1;
  unsigned* q0 = reinterpret_cast<unsigned*>(&o0);
  unsigned* q1 = reinterpret_cast<unsigned*>(&o1);
  #pragma unroll
  for (int q = 0; q < 4; ++q) {
    q0[q] = cvtpk(s[2 * q] * inv, s[2 * q + 1] * inv);
    q1[q] = cvtpk(s[8 + 2 * q] * inv, s[8 + 2 * q + 1] * inv);
  }
  uint4* dst = reinterpret_cast<uint4*>(ws + (size_t)(132 + b) * IS + off);
  dst[0] = o0;
  dst[1] = o1;
}

// ================= kernel C: LDS double-buffered DMA conv =================

// stage one image (4 input rows, clamped) into one 32KB LDS buffer
__device__ __forceinline__ void stage_img(char* __restrict__ ldsbuf,
                                          const char* __restrict__ imgbase,
                                          int y, int w, int lane)
{
  #pragma unroll
  for (int j = 0; j < 4; ++j) {
    const int c = w * 4 + j;                 // 0..31 chunks of 1KB
    const int ri = c >> 3, kc4 = (c >> 1) & 3, half = c & 1;
    int sr = y - 1 + ri;
    sr = sr < 0 ? 0 : (sr > 127 ? 127 : sr);
    const char* src = imgbase + (size_t)sr * 8192 + kc4 * 2048 + half * 1024 + lane * 16;
    char* dst = ldsbuf + ri * 8192 + kc4 * 2048 + half * 1024;
    GLD16(src, dst);
  }
}

__device__ __forceinline__ bf16x8 ld_frag(const char* __restrict__ buf,
                                          int ri, int kc, int s)
{
  return *reinterpret_cast<const bf16x8*>(buf + ri * 8192 + kc * 2048 + s * 16);
}

// conv one image from LDS buffer into acc[2 rows][2 n-tiles]
__device__ __forceinline__ void conv_one(f32x4 acc[2][2],
                                         const char* __restrict__ buf,
                                         const bf16x8 wf[9],
                                         int sbase, int kc,
                                         bool rok0, bool rok3)
{
  #pragma unroll
  for (int ri = 0; ri < 4; ++ri) {
    bf16x8 F[6];   // [n*3+kx]
    {
      const int s = sbase - 1;
      const int sc = s < 0 ? 0 : s;
      bf16x8 v = ld_frag(buf, ri, kc, sc);
      if (s < 0) v = bf16x8{0, 0, 0, 0, 0, 0, 0, 0};
      F[0] = v;
    }
    F[1] = ld_frag(buf, ri, kc, sbase);
    F[2] = ld_frag(buf, ri, kc, sbase + 1);
    F[3] = ld_frag(buf, ri, kc, sbase + 15);
    F[4] = ld_frag(buf, ri, kc, sbase + 16);
    {
      const int s = sbase + 17;
      const int sc = s > 127 ? 127 : s;
      bf16x8 v = ld_frag(buf, ri, kc, sc);
      if (s > 127) v = bf16x8{0, 0, 0, 0, 0, 0, 0, 0};
      F[5] = v;
    }
    const bool u0 = (ri <= 2) && (ri != 0 || rok0);   // out row 0, ky = ri
    const bool u1 = (ri >= 1) && (ri != 3 || rok3);   // out row 1, ky = ri-1
    if (u0) {
      #pragma unroll
      for (int kx = 0; kx < 3; ++kx)
        #pragma unroll
        for (int n = 0; n < 2; ++n)
          acc[0][n] = __builtin_amdgcn_mfma_f32_16x16x32_bf16(wf[ri * 3 + kx], F[n * 3 + kx], acc[0][n], 0, 0, 0);
    }
    if (u1) {
      #pragma unroll
      for (int kx = 0; kx < 3; ++kx)
        #pragma unroll
        for (int n = 0; n < 2; ++n)
          acc[1][n] = __builtin_amdgcn_mfma_f32_16x16x32_bf16(wf[(ri - 1) * 3 + kx], F[n * 3 + kx], acc[1][n], 0, 0, 0);
    }
  }
}

template <bool NTMEAN>
__global__ __launch_bounds__(512, 4)
void conv_lds(const unsigned short* __restrict__ ws,
              const float* __restrict__ Wfull,
              const float* __restrict__ bias,
              float* __restrict__ out)
{
  __shared__ char lds[2 * 32768];

  const int tid = threadIdx.x, lane = tid & 63, w = tid >> 6;
  const int pxq = w & 3, m = w >> 2;
  const int lx = lane & 15, kc = lane >> 4;

  // bijective XCD swizzle over 1024 blocks (1024 % 8 == 0)
  const int orig = blockIdx.x;
  const int eff  = (orig & 7) * 128 + (orig >> 3);
  const int yp  = eff & 63;
  const int syq = (eff >> 6) & 3;
  const int b   = eff >> 8;

  const int y  = yp * 2;
  const bool rok0 = (y > 0), rok3 = (y < 126);
  const int sbase = pxq * 32 + lx;      // base px slot for this lane

  const char* tgt  = (const char*)(ws + (size_t)(Bb * SY + b) * IS);
  const char* sup0 = (const char*)(ws + (size_t)(b * SY + syq * 8) * IS);
  const char* mnp  = (const char*)(ws + (size_t)(132 + b) * IS);

  // this block also computes new_target rows (balanced across syq)
  const bool doNT = NTMEAN && (syq == (yp & 3));
  const int nimg = doNT ? 9 : 8;        // image 8 == mean image

  bf16x8 wf[9];
  load_w(wf, Wfull, 0, m, lane);                    // Wx

  // ---- target -> buf0, compute cx (= conv_Wx(target) + bias) ----
  stage_img(lds, tgt, y, w, lane);
  WAITV(0);
  __syncthreads();

  f32x4 cx[2][2];
  #pragma unroll
  for (int r2 = 0; r2 < 2; ++r2)
    #pragma unroll
    for (int n = 0; n < 2; ++n) cx[r2][n] = f32x4{0.f, 0.f, 0.f, 0.f};
  conv_one(cx, lds, wf, sbase, kc, rok0, rok3);
  #pragma unroll
  for (int j = 0; j < 4; ++j) {
    const float bvv = bias[m * 16 + kc * 4 + j];
    #pragma unroll
    for (int r2 = 0; r2 < 2; ++r2)
      #pragma unroll
      for (int n = 0; n < 2; ++n) cx[r2][n][j] += bvv;
  }
  load_w(wf, Wfull, 32, m, lane);                   // Wy

  BARX();                                           // all waves done reading buf0

  // ---- prologue: stage img0 -> buf0, img1 -> buf1 ----
  stage_img(lds,         sup0,                  y, w, lane);
  stage_img(lds + 32768, sup0 + (size_t)IS * 2, y, w, lane);
  WAITV(4);                                         // img0's 4 loads done
  BARX();

  f32x4 sum[2][2];
  if constexpr (!NTMEAN) {
    #pragma unroll
    for (int r2 = 0; r2 < 2; ++r2)
      #pragma unroll
      for (int n = 0; n < 2; ++n) sum[r2][n] = f32x4{0.f, 0.f, 0.f, 0.f};
  }

  for (int i = 0; i < nimg; ++i) {
    const char* cb = lds + (i & 1) * 32768;

    f32x4 acc[2][2];
    #pragma unroll
    for (int r2 = 0; r2 < 2; ++r2)
      #pragma unroll
      for (int n = 0; n < 2; ++n) acc[r2][n] = cx[r2][n];
    conv_one(acc, cb, wf, sbase, kc, rok0, rok3);

    if (!NTMEAN || i < 8) {
      const int sy = syq * 8 + i;
      #pragma unroll
      for (int r2 = 0; r2 < 2; ++r2)
        #pragma unroll
        for (int n = 0; n < 2; ++n) {
          if constexpr (!NTMEAN) sum[r2][n] += acc[r2][n];
          const size_t basei = (size_t)NT +
              (((size_t)(b * SY + sy) * CO + m * 16 + kc * 4) * Himg + y + r2) * Wimg +
              pxq * 32 + n * 16 + lx;
          #pragma unroll
          for (int j = 0; j < 4; ++j)
            out[basei + (size_t)j * IMG] = acc[r2][n][j];
        }
    } else {
      // mean image: acc = cx + bias + conv_Wy(mean) == new_target rows
      #pragma unroll
      for (int r2 = 0; r2 < 2; ++r2)
        #pragma unroll
        for (int n = 0; n < 2; ++n) {
          const size_t baseo =
              ((size_t)(b * CO + m * 16 + kc * 4) * Himg + y + r2) * Wimg +
              pxq * 32 + n * 16 + lx;
          #pragma unroll
          for (int j = 0; j < 4; ++j)
            out[baseo + (size_t)j * IMG] = acc[r2][n][j];
        }
    }

    BARX();                                         // all waves done reading cb
    if (i + 2 < nimg) {
      const char* nsrc = (i + 2 < 8) ? sup0 + (size_t)(i + 2) * IS * 2 : mnp;
      stage_img(lds + (i & 1) * 32768, nsrc, y, w, lane);
    }
    WAITV(4);                                       // img i+1 staged
    BARX();
  }

  if constexpr (!NTMEAN) {
    // new_target partial (4 syq partials per element)
    #pragma unroll
    for (int r2 = 0; r2 < 2; ++r2)
      #pragma unroll
      for (int n = 0; n < 2; ++n) {
        const size_t baseo =
            ((size_t)(b * CO + m * 16 + kc * 4) * Himg + y + r2) * Wimg + pxq * 32 + n * 16 + lx;
        #pragma unroll
        for (int j = 0; j < 4; ++j) {
          const float cyPart = (sum[r2][n][j] - 8.f * cx[r2][n][j]) * (1.f / 32.f);
          const float v = cyPart + (syq == 0 ? cx[r2][n][j] : 0.f);
          atomicAdd(&out[baseo + (size_t)j * IMG], v);
        }
      }
  }
}

// ============ fallback (round-4 kernel, used only if ws too small) ============
constexpr int TROWS = 6, TQ = 17, TCOLS = 70;
constexpr int NPIX  = TROWS * TCOLS;
constexpr int LDSB  = NPIX * 64;
constexpr int RTASK = TROWS * TQ;
constexpr int FB_NTHR = 512;
constexpr int FB_TPT  = 4;
constexpr int FB_SYC  = 8;

__device__ __forceinline__ int fb_swz(int pix, int cb) {
  return (pix * 64 + cb) ^ ((pix & 7) << 4);
}
__device__ __forceinline__ void fb_task_decode(int t, int& ch, int& row, int& q, bool& act) {
  ch = t & 15;
  const int r = t >> 4;
  row = r / TQ;
  q   = r - row * TQ;
  act = (r < RTASK);
}
__device__ __forceinline__ void fb_stage_load(f32x4 va[FB_TPT], f32x4 vb[FB_TPT],
                                              const float* __restrict__ src,
                                              int y0, int xq0, int tid)
{
  #pragma unroll
  for (int k = 0; k < FB_TPT; ++k) {
    int ch, row, q; bool act;
    fb_task_decode(tid + k * FB_NTHR, ch, row, q, act);
    const int y = y0 - 1 + row;
    act = act && ((unsigned)y < (unsigned)Himg);
    f32x4 v0 = {0.f, 0.f, 0.f, 0.f}, v1 = {0.f, 0.f, 0.f, 0.f};
    if (act) {
      const float* p = src + (size_t)(2 * ch) * IMG + y * Wimg + 4 * (xq0 + q);
      v0 = *reinterpret_cast<const f32x4*>(p);
      v1 = *reinterpret_cast<const f32x4*>(p + IMG);
    }
    va[k] = v0; vb[k] = v1;
  }
}
__device__ __forceinline__ void fb_stage_write(const f32x4 va[FB_TPT], const f32x4 vb[FB_TPT],
                                               char* __restrict__ lds,
                                               int y0, int xq0, int x0, int tid)
{
  #pragma unroll
  for (int k = 0; k < FB_TPT; ++k) {
    int ch, row, q; bool act;
    fb_task_decode(tid + k * FB_NTHR, ch, row, q, act);
    const int y = y0 - 1 + row;
    act = act && ((unsigned)y < (unsigned)Himg);
    if (act) {
      const int ix0 = 4 * (xq0 + q) - x0 + 1;
      #pragma unroll
      for (int e = 0; e < 4; ++e) {
        const int ix = ix0 + e;
        if (ix >= 0) {
          const int pix = row * TCOLS + ix;
          *reinterpret_cast<unsigned*>(lds + fb_swz(pix, ch * 4)) =
              cvtpk(va[k][e], vb[k][e]);
        }
      }
    }
  }
}
__device__ __forceinline__ void fb_conv1(f32x4 acc[4],
                                         const char* __restrict__ lds,
                                         const bf16x8 wf[9],
                                         int row, int lane)
{
  const int lx = lane & 15, kc = lane >> 4;
  #pragma unroll
  for (int ky = 0; ky < 3; ++ky) {
    #pragma unroll
    for (int kx = 0; kx < 3; ++kx) {
      const int tap = ky * 3 + kx;
      #pragma unroll
      for (int n = 0; n < 4; ++n) {
        const int p = (row + ky) * TCOLS + n * 16 + lx + kx;
        const bf16x8 bfrag = *reinterpret_cast<const bf16x8*>(lds + fb_swz(p, kc * 16));
        acc[n] = __builtin_amdgcn_mfma_f32_16x16x32_bf16(wf[tap], bfrag, acc[n], 0, 0, 0);
      }
    }
  }
}
__global__ __launch_bounds__(FB_NTHR, 4)
void fb_cross_mfma(const float* __restrict__ target,
                   const float* __restrict__ support,
                   const float* __restrict__ Wfull,
                   const float* __restrict__ bias,
                   float* __restrict__ out)
{
  __shared__ char lds[LDSB];
  const int tid  = threadIdx.x;
  const int lane = tid & 63;
  const int wv   = tid >> 6;
  const int row  = wv & 3;
  const int m    = wv >> 2;
  const int lx = lane & 15, kc = lane >> 4;
  const int bid = blockIdx.x;
  const int syq = bid & 3;
  const int xh  = (bid >> 2) & 1;
  const int yb  = (bid >> 3) & 31;
  const int b   = bid >> 8;
  const int y0 = yb * 4, x0 = xh * 64;
  const int y  = y0 + row;
  const int xq0 = xh ? 15 : 0;

  for (int e = tid; e < NPIX * 4; e += FB_NTHR)
    reinterpret_cast<f32x4*>(lds)[e] = f32x4{0.f, 0.f, 0.f, 0.f};

  bf16x8 wf[9];
  load_w(wf, Wfull, 0, m, lane);
  f32x4 va[FB_TPT], vb[FB_TPT];
  fb_stage_load(va, vb, target + (size_t)b * CIN * IMG, y0, xq0, tid);
  __syncthreads();
  fb_stage_write(va, vb, lds, y0, xq0, x0, tid);
  __syncthreads();

  f32x4 cx[4];
  #pragma unroll
  for (int n = 0; n < 4; ++n) cx[n] = f32x4{0.f, 0.f, 0.f, 0.f};
  fb_conv1(cx, lds, wf, row, lane);
  #pragma unroll
  for (int j = 0; j < 4; ++j) {
    const float bvv = bias[m * 16 + kc * 4 + j];
    #pragma unroll
    for (int n = 0; n < 4; ++n) cx[n][j] += bvv;
  }

  const float* supp0 = support + (size_t)(b * SY + syq * FB_SYC) * CIN * IMG;
  fb_stage_load(va, vb, supp0, y0, xq0, tid);
  load_w(wf, Wfull, 32, m, lane);
  __syncthreads();
  fb_stage_write(va, vb, lds, y0, xq0, x0, tid);

  f32x4 sum[4];
  #pragma unroll
  for (int n = 0; n < 4; ++n) sum[n] = f32x4{0.f, 0.f, 0.f, 0.f};
  __syncthreads();

  for (int i = 0; i < FB_SYC; ++i) {
    if (i < FB_SYC - 1)
      fb_stage_load(va, vb, supp0 + (size_t)(i + 1) * CIN * IMG, y0, xq0, tid);

    f32x4 acc[4];
    #pragma unroll
    for (int n = 0; n < 4; ++n) acc[n] = cx[n];
    fb_conv1(acc, lds, wf, row, lane);
    __syncthreads();

    if (i < FB_SYC - 1)
      fb_stage_write(va, vb, lds, y0, xq0, x0, tid);

    const int sy = syq * FB_SYC + i;
    #pragma unroll
    for (int n = 0; n < 4; ++n) {
      sum[n] += acc[n];
      const size_t basei = (size_t)NT +
          (((size_t)(b * SY + sy) * CO + m * 16 + kc * 4) * Himg + y) * Wimg +
          x0 + n * 16 + lx;
      #pragma unroll
      for (int j = 0; j < 4; ++j)
        out[basei + (size_t)j * IMG] = acc[n][j];
    }
    __syncthreads();
  }

  #pragma unroll
  for (int n = 0; n < 4; ++n) {
    const size_t baseo =
        ((size_t)(b * CO + m * 16 + kc * 4) * Himg + y) * Wimg + x0 + n * 16 + lx;
    #pragma unroll
    for (int j = 0; j < 4; ++j) {
      const float cyPart = (sum[n][j] - (float)FB_SYC * cx[n][j]) * (1.f / 32.f);
      const float v = cyPart + (syq == 0 ? cx[n][j] : 0.f);
      atomicAdd(&out[baseo + (size_t)j * IMG], v);
    }
  }
}

} // namespace

extern "C" void kernel_launch(void* const* d_in, const int* in_sizes, int n_in,
                              void* d_out, int out_size, void* d_ws, size_t ws_size,
                              hipStream_t stream)
{
  (void)in_sizes; (void)n_in; (void)out_size;
  const float* target  = (const float*)d_in[0];
  const float* support = (const float*)d_in[1];
  const float* Wfull   = (const float*)d_in[2];
  const float* bias    = (const float*)d_in[3];
  float* out = (float*)d_out;

  if (ws_size >= WS2) {
    // mean path: every output element written exactly once -> no memset, no atomics
    unsigned short* ws = (unsigned short*)d_ws;
    transform_nhwc<<<dim3((Bb * SY + Bb) * 64), 256, 0, stream>>>(target, support, ws);
    mean_k<<<dim3(512), 256, 0, stream>>>(ws);
    conv_lds<true><<<dim3(1024), 512, 0, stream>>>(ws, Wfull, bias, out);
  } else if (ws_size >= WS1) {
    unsigned short* ws = (unsigned short*)d_ws;
    hipMemsetAsync(d_out, 0, (size_t)NT * sizeof(float), stream);
    transform_nhwc<<<dim3((Bb * SY + Bb) * 64), 256, 0, stream>>>(target, support, ws);
    conv_lds<false><<<dim3(1024), 512, 0, stream>>>(ws, Wfull, bias, out);
  } else {
    hipMemsetAsync(d_out, 0, (size_t)NT * sizeof(float), stream);
    fb_cross_mfma<<<dim3(1024), FB_NTHR, 0, stream>>>(target, support, Wfull, bias, out);
  }
}

// Round 14
// 215.379 us; speedup vs baseline: 1.8124x; 1.1131x over previous
//
#include <hip/hip_runtime.h>

typedef short bf16x8 __attribute__((ext_vector_type(8)));
typedef float f32x4  __attribute__((ext_vector_type(4)));

namespace {

constexpr int CIN = 32, CO = 32, Himg = 128, Wimg = 128, SY = 32, Bb = 4;
constexpr int IMG = Himg * Wimg;                 // 16384
constexpr int NT  = Bb * CO * IMG;               // new_target elems
constexpr size_t IS = (size_t)IMG * CIN;         // 524288 shorts per ws image (1 MB)
// ws layout: img 0..127 = support, 128..131 = target, 132..135 = mean(support) per b
// image layout: [row y][plane kc(4)][px(128)][ci8] -> row 8192 B, plane 2048 B
constexpr size_t WS1 = (size_t)132 * IS * 2;     // 138,412,032 B (no-mean path)
constexpr size_t WS2 = (size_t)136 * IS * 2;     // 142,606,336 B (mean path)

__device__ __forceinline__ unsigned cvtpk(float lo, float hi) {
  unsigned r;
  asm("v_cvt_pk_bf16_f32 %0, %1, %2" : "=v"(r) : "v"(lo), "v"(hi));
  return r;
}

#define GLD16(g, l)                                                        \
  __builtin_amdgcn_global_load_lds(                                       \
      (const __attribute__((address_space(1))) void*)(g),                 \
      (__attribute__((address_space(3))) void*)(l), 16, 0, 0)

#define FENCE() asm volatile("" ::: "memory")
#define SB0()   __builtin_amdgcn_sched_barrier(0)
#define BARX()                          \
  do {                                  \
    FENCE();                            \
    __builtin_amdgcn_s_barrier();       \
    FENCE();                            \
    SB0();                              \
  } while (0)
#define WAITV(n) asm volatile("s_waitcnt vmcnt(" #n ")" ::: "memory")

// per-lane A fragments (weights) for one co-tile m; ci = cioff + kc*8 + j
__device__ __forceinline__ void load_w(bf16x8 wf[9],
                                       const float* __restrict__ Wfull,
                                       int cioff, int m, int lane)
{
  const int lx = lane & 15, kc = lane >> 4;
  #pragma unroll
  for (int tap = 0; tap < 9; ++tap) {
    const float* base = Wfull + (size_t)((m * 16 + lx) * 64 + cioff + kc * 8) * 9 + tap;
    bf16x8 w;
    #pragma unroll
    for (int j = 0; j < 8; ++j) {
      unsigned u = __builtin_bit_cast(unsigned, base[j * 9]);
      w[j] = (short)((u + 0x7FFFu + ((u >> 16) & 1u)) >> 16);
    }
    wf[tap] = w;
  }
}

// ================= kernel T: NCHW f32 -> plane-major NHWC bf16 =================
__global__ __launch_bounds__(256)
void transform_nhwc(const float* __restrict__ target,
                    const float* __restrict__ support,
                    unsigned short* __restrict__ ws)
{
  __shared__ unsigned lbuf[256 * 17];

  const int tid   = threadIdx.x;
  const int img   = blockIdx.x >> 6;
  const int chunk = blockIdx.x & 63;
  const float* src = (img < Bb * SY)
      ? support + (size_t)img * CIN * IMG
      : target  + (size_t)(img - Bb * SY) * CIN * IMG;
  const int y0 = chunk * 2;

  f32x4 a[4], bv[4];
  #pragma unroll
  for (int k = 0; k < 4; ++k) {
    const int task = tid + k * 256;
    const int c2 = task >> 6, quad = task & 63;
    const float* p = src + (size_t)(2 * c2) * IMG + y0 * Wimg + quad * 4;
    a[k]  = *reinterpret_cast<const f32x4*>(p);
    bv[k] = *reinterpret_cast<const f32x4*>(p + IMG);
  }
  #pragma unroll
  for (int k = 0; k < 4; ++k) {
    const int task = tid + k * 256;
    const int c2 = task >> 6, quad = task & 63;
    #pragma unroll
    for (int e = 0; e < 4; ++e) {
      const int px = quad * 4 + e;   // 0..255 linear over 2 rows
      lbuf[px * 17 + (c2 ^ ((px >> 2) & 15))] = cvtpk(a[k][e], bv[k][e]);
    }
  }
  __syncthreads();

  #pragma unroll
  for (int k = 0; k < 4; ++k) {
    const int G = tid + k * 256;            // 0..1023
    const int r  = G >> 9;
    const int kc = (G >> 7) & 3;
    const int px = G & 127;
    const int pl = r * 128 + px;
    uint4 v;
    unsigned* vp = reinterpret_cast<unsigned*>(&v);
    #pragma unroll
    for (int w = 0; w < 4; ++w)
      vp[w] = lbuf[pl * 17 + ((kc * 4 + w) ^ ((pl >> 2) & 15))];
    unsigned short* dst = ws + (size_t)img * IS + (size_t)(y0 + r) * 4096 + kc * 1024 + px * 8;
    *reinterpret_cast<uint4*>(dst) = v;
  }
}

// ============ kernel M: mean over sy of ws support (bf16, elementwise) ============
__global__ __launch_bounds__(256)
void mean_k(unsigned short* __restrict__ ws)
{
  const int b = blockIdx.x >> 7, y = blockIdx.x & 127;
  const size_t off = (size_t)y * 4096 + threadIdx.x * 16;   // 16 shorts per thread

  float s[16];
  #pragma unroll
  for (int k = 0; k < 16; ++k) s[k] = 0.f;

  #pragma unroll 4
  for (int sy = 0; sy < SY; ++sy) {
    const uint4* p = reinterpret_cast<const uint4*>(ws + (size_t)(b * SY + sy) * IS + off);
    uint4 v0 = p[0], v1 = p[1];
    const unsigned* w0 = reinterpret_cast<const unsigned*>(&v0);
    const unsigned* w1 = reinterpret_cast<const unsigned*>(&v1);
    #pragma unroll
    for (int q = 0; q < 4; ++q) {
      s[2 * q + 0] += __builtin_bit_cast(float, w0[q] << 16);
      s[2 * q + 1] += __builtin_bit_cast(float, w0[q] & 0xffff0000u);
      s[8 + 2 * q + 0] += __builtin_bit_cast(float, w1[q] << 16);
      s[8 + 2 * q + 1] += __builtin_bit_cast(float, w1[q] & 0xffff0000u);
    }
  }

  constexpr float inv = 1.0f / SY;
  uint4 o0, o1;
  unsigned* q0 = reinterpret_cast<unsigned*>(&o0);
  unsigned* q1 = reinterpret_cast<unsigned*>(&o1);
  #pragma unroll
  for (int q = 0; q < 4; ++q) {
    q0[q] = cvtpk(s[2 * q] * inv, s[2 * q + 1] * inv);
    q1[q] = cvtpk(s[8 + 2 * q] * inv, s[8 + 2 * q + 1] * inv);
  }
  uint4* dst = reinterpret_cast<uint4*>(ws + (size_t)(132 + b) * IS + off);
  dst[0] = o0;
  dst[1] = o1;
}

// ================= kernel C: LDS double-buffered DMA conv =================

// stage one image (4 input rows, clamped) into one 32KB LDS buffer: 4 vmem ops/thread
__device__ __forceinline__ void stage_img(char* __restrict__ ldsbuf,
                                          const char* __restrict__ imgbase,
                                          int y, int w, int lane)
{
  #pragma unroll
  for (int j = 0; j < 4; ++j) {
    const int c = w * 4 + j;                 // 0..31 chunks of 1KB
    const int ri = c >> 3, kc4 = (c >> 1) & 3, half = c & 1;
    int sr = y - 1 + ri;
    sr = sr < 0 ? 0 : (sr > 127 ? 127 : sr);
    const char* src = imgbase + (size_t)sr * 8192 + kc4 * 2048 + half * 1024 + lane * 16;
    char* dst = ldsbuf + ri * 8192 + kc4 * 2048 + half * 1024;
    GLD16(src, dst);
  }
}

__device__ __forceinline__ bf16x8 ld_frag(const char* __restrict__ buf,
                                          int ri, int kc, int s)
{
  return *reinterpret_cast<const bf16x8*>(buf + ri * 8192 + kc * 2048 + s * 16);
}

// conv one image from LDS buffer into acc[2 rows][2 n-tiles]
__device__ __forceinline__ void conv_one(f32x4 acc[2][2],
                                         const char* __restrict__ buf,
                                         const bf16x8 wf[9],
                                         int sbase, int kc,
                                         bool rok0, bool rok3)
{
  #pragma unroll
  for (int ri = 0; ri < 4; ++ri) {
    bf16x8 F[6];   // [n*3+kx]
    {
      const int s = sbase - 1;
      const int sc = s < 0 ? 0 : s;
      bf16x8 v = ld_frag(buf, ri, kc, sc);
      if (s < 0) v = bf16x8{0, 0, 0, 0, 0, 0, 0, 0};
      F[0] = v;
    }
    F[1] = ld_frag(buf, ri, kc, sbase);
    F[2] = ld_frag(buf, ri, kc, sbase + 1);
    F[3] = ld_frag(buf, ri, kc, sbase + 15);
    F[4] = ld_frag(buf, ri, kc, sbase + 16);
    {
      const int s = sbase + 17;
      const int sc = s > 127 ? 127 : s;
      bf16x8 v = ld_frag(buf, ri, kc, sc);
      if (s > 127) v = bf16x8{0, 0, 0, 0, 0, 0, 0, 0};
      F[5] = v;
    }
    const bool u0 = (ri <= 2) && (ri != 0 || rok0);   // out row 0, ky = ri
    const bool u1 = (ri >= 1) && (ri != 3 || rok3);   // out row 1, ky = ri-1
    if (u0) {
      #pragma unroll
      for (int kx = 0; kx < 3; ++kx)
        #pragma unroll
        for (int n = 0; n < 2; ++n)
          acc[0][n] = __builtin_amdgcn_mfma_f32_16x16x32_bf16(wf[ri * 3 + kx], F[n * 3 + kx], acc[0][n], 0, 0, 0);
    }
    if (u1) {
      #pragma unroll
      for (int kx = 0; kx < 3; ++kx)
        #pragma unroll
        for (int n = 0; n < 2; ++n)
          acc[1][n] = __builtin_amdgcn_mfma_f32_16x16x32_bf16(wf[(ri - 1) * 3 + kx], F[n * 3 + kx], acc[1][n], 0, 0, 0);
    }
  }
}

template <bool NTMEAN>
__global__ __launch_bounds__(512, 4)
void conv_lds(const unsigned short* __restrict__ ws,
              const float* __restrict__ Wfull,
              const float* __restrict__ bias,
              float* __restrict__ out)
{
  __shared__ char lds[2 * 32768];

  const int tid = threadIdx.x, lane = tid & 63, w = tid >> 6;
  const int pxq = w & 3, m = w >> 2;
  const int lx = lane & 15, kc = lane >> 4;

  // bijective XCD swizzle over 1024 blocks (1024 % 8 == 0)
  const int orig = blockIdx.x;
  const int eff  = (orig & 7) * 128 + (orig >> 3);
  const int yp  = eff & 63;
  const int syq = (eff >> 6) & 3;
  const int b   = eff >> 8;

  const int y  = yp * 2;
  const bool rok0 = (y > 0), rok3 = (y < 126);
  const int sbase = pxq * 32 + lx;      // base px slot for this lane

  const char* tgt  = (const char*)(ws + (size_t)(Bb * SY + b) * IS);
  const char* sup0 = (const char*)(ws + (size_t)(b * SY + syq * 8) * IS);
  const char* mnp  = (const char*)(ws + (size_t)(132 + b) * IS);

  // this block also computes new_target rows (balanced across syq)
  const bool doNT = NTMEAN && (syq == (yp & 3));
  const int nimg = doNT ? 9 : 8;        // image 8 == mean image

  bf16x8 wf[9];
  load_w(wf, Wfull, 0, m, lane);                    // Wx

  // ---- target -> buf0, compute cx (= conv_Wx(target) + bias) ----
  stage_img(lds, tgt, y, w, lane);
  WAITV(0);
  __syncthreads();

  f32x4 cx[2][2];
  #pragma unroll
  for (int r2 = 0; r2 < 2; ++r2)
    #pragma unroll
    for (int n = 0; n < 2; ++n) cx[r2][n] = f32x4{0.f, 0.f, 0.f, 0.f};
  conv_one(cx, lds, wf, sbase, kc, rok0, rok3);
  #pragma unroll
  for (int j = 0; j < 4; ++j) {
    const float bvv = bias[m * 16 + kc * 4 + j];
    #pragma unroll
    for (int r2 = 0; r2 < 2; ++r2)
      #pragma unroll
      for (int n = 0; n < 2; ++n) cx[r2][n][j] += bvv;
  }
  load_w(wf, Wfull, 32, m, lane);                   // Wy

  BARX();                                           // all waves done reading buf0

  // ---- prologue: stage img0 -> buf0, img1 -> buf1 ----
  stage_img(lds,         sup0,                  y, w, lane);
  stage_img(lds + 32768, sup0 + (size_t)IS * 2, y, w, lane);
  WAITV(4);                                         // img0's 4 loads done (Wy drained too)
  BARX();

  f32x4 sum[2][2];
  if constexpr (!NTMEAN) {
    #pragma unroll
    for (int r2 = 0; r2 < 2; ++r2)
      #pragma unroll
      for (int n = 0; n < 2; ++n) sum[r2][n] = f32x4{0.f, 0.f, 0.f, 0.f};
  }

  // Steady-state vmcnt FIFO per wave: ... L_{i+1}(4) S_{i-1}(16) L_{i+2}(4) S_i(16)
  // WAITV(36) at end of iter i retires exactly through L_{i+1}; stores never drain.
  for (int i = 0; i < nimg; ++i) {
    const char* cb = lds + (i & 1) * 32768;

    f32x4 acc[2][2];
    #pragma unroll
    for (int r2 = 0; r2 < 2; ++r2)
      #pragma unroll
      for (int n = 0; n < 2; ++n) acc[r2][n] = cx[r2][n];
    conv_one(acc, cb, wf, sbase, kc, rok0, rok3);

    BARX();                                         // all waves done reading cb

    const bool more = (i + 2 < nimg);
    if (more) {                                     // stage img i+2 over cb: 4 loads
      const char* nsrc = (i + 2 < 8) ? sup0 + (size_t)(i + 2) * IS * 2 : mnp;
      stage_img(lds + (i & 1) * 32768, nsrc, y, w, lane);
    }
    SB0();                                          // pin: loads issued before stores

    if (!NTMEAN || i < 8) {
      const int sy = syq * 8 + i;
      #pragma unroll
      for (int r2 = 0; r2 < 2; ++r2)
        #pragma unroll
        for (int n = 0; n < 2; ++n) {
          if constexpr (!NTMEAN) sum[r2][n] += acc[r2][n];
          const size_t basei = (size_t)NT +
              (((size_t)(b * SY + sy) * CO + m * 16 + kc * 4) * Himg + y + r2) * Wimg +
              pxq * 32 + n * 16 + lx;
          #pragma unroll
          for (int j = 0; j < 4; ++j)
            out[basei + (size_t)j * IMG] = acc[r2][n][j];
        }
    } else {
      // mean image: acc = cx + bias + conv_Wy(mean) == new_target rows
      #pragma unroll
      for (int r2 = 0; r2 < 2; ++r2)
        #pragma unroll
        for (int n = 0; n < 2; ++n) {
          const size_t baseo =
              ((size_t)(b * CO + m * 16 + kc * 4) * Himg + y + r2) * Wimg +
              pxq * 32 + n * 16 + lx;
          #pragma unroll
          for (int j = 0; j < 4; ++j)
            out[baseo + (size_t)j * IMG] = acc[r2][n][j];
        }
    }

    // counted wait: retire through L_{i+1} only; stores stay in flight
    if (i + 1 < nimg) {
      if (i == 0)       WAITV(20);   // after L_1: L_2(4)+S_0(16)
      else if (more)    WAITV(36);   // after L_{i+1}: S_{i-1}+L_{i+2}+S_i
      else              WAITV(32);   // tail (no L issued): S_{i-2}+S_{i-1}... = 32
      BARX();                        // buf[(i+1)&1] visible to all waves
    }
  }

  if constexpr (!NTMEAN) {
    // new_target partial (4 syq partials per element)
    #pragma unroll
    for (int r2 = 0; r2 < 2; ++r2)
      #pragma unroll
      for (int n = 0; n < 2; ++n) {
        const size_t baseo =
            ((size_t)(b * CO + m * 16 + kc * 4) * Himg + y + r2) * Wimg + pxq * 32 + n * 16 + lx;
        #pragma unroll
        for (int j = 0; j < 4; ++j) {
          const float cyPart = (sum[r2][n][j] - 8.f * cx[r2][n][j]) * (1.f / 32.f);
          const float v = cyPart + (syq == 0 ? cx[r2][n][j] : 0.f);
          atomicAdd(&out[baseo + (size_t)j * IMG], v);
        }
      }
  }
}

// ============ fallback (round-4 kernel, used only if ws too small) ============
constexpr int TROWS = 6, TQ = 17, TCOLS = 70;
constexpr int NPIX  = TROWS * TCOLS;
constexpr int LDSB  = NPIX * 64;
constexpr int RTASK = TROWS * TQ;
constexpr int FB_NTHR = 512;
constexpr int FB_TPT  = 4;
constexpr int FB_SYC  = 8;

__device__ __forceinline__ int fb_swz(int pix, int cb) {
  return (pix * 64 + cb) ^ ((pix & 7) << 4);
}
__device__ __forceinline__ void fb_task_decode(int t, int& ch, int& row, int& q, bool& act) {
  ch = t & 15;
  const int r = t >> 4;
  row = r / TQ;
  q   = r - row * TQ;
  act = (r < RTASK);
}
__device__ __forceinline__ void fb_stage_load(f32x4 va[FB_TPT], f32x4 vb[FB_TPT],
                                              const float* __restrict__ src,
                                              int y0, int xq0, int tid)
{
  #pragma unroll
  for (int k = 0; k < FB_TPT; ++k) {
    int ch, row, q; bool act;
    fb_task_decode(tid + k * FB_NTHR, ch, row, q, act);
    const int y = y0 - 1 + row;
    act = act && ((unsigned)y < (unsigned)Himg);
    f32x4 v0 = {0.f, 0.f, 0.f, 0.f}, v1 = {0.f, 0.f, 0.f, 0.f};
    if (act) {
      const float* p = src + (size_t)(2 * ch) * IMG + y * Wimg + 4 * (xq0 + q);
      v0 = *reinterpret_cast<const f32x4*>(p);
      v1 = *reinterpret_cast<const f32x4*>(p + IMG);
    }
    va[k] = v0; vb[k] = v1;
  }
}
__device__ __forceinline__ void fb_stage_write(const f32x4 va[FB_TPT], const f32x4 vb[FB_TPT],
                                               char* __restrict__ lds,
                                               int y0, int xq0, int x0, int tid)
{
  #pragma unroll
  for (int k = 0; k < FB_TPT; ++k) {
    int ch, row, q; bool act;
    fb_task_decode(tid + k * FB_NTHR, ch, row, q, act);
    const int y = y0 - 1 + row;
    act = act && ((unsigned)y < (unsigned)Himg);
    if (act) {
      const int ix0 = 4 * (xq0 + q) - x0 + 1;
      #pragma unroll
      for (int e = 0; e < 4; ++e) {
        const int ix = ix0 + e;
        if (ix >= 0) {
          const int pix = row * TCOLS + ix;
          *reinterpret_cast<unsigned*>(lds + fb_swz(pix, ch * 4)) =
              cvtpk(va[k][e], vb[k][e]);
        }
      }
    }
  }
}
__device__ __forceinline__ void fb_conv1(f32x4 acc[4],
                                         const char* __restrict__ lds,
                                         const bf16x8 wf[9],
                                         int row, int lane)
{
  const int lx = lane & 15, kc = lane >> 4;
  #pragma unroll
  for (int ky = 0; ky < 3; ++ky) {
    #pragma unroll
    for (int kx = 0; kx < 3; ++kx) {
      const int tap = ky * 3 + kx;
      #pragma unroll
      for (int n = 0; n < 4; ++n) {
        const int p = (row + ky) * TCOLS + n * 16 + lx + kx;
        const bf16x8 bfrag = *reinterpret_cast<const bf16x8*>(lds + fb_swz(p, kc * 16));
        acc[n] = __builtin_amdgcn_mfma_f32_16x16x32_bf16(wf[tap], bfrag, acc[n], 0, 0, 0);
      }
    }
  }
}
__global__ __launch_bounds__(FB_NTHR, 4)
void fb_cross_mfma(const float* __restrict__ target,
                   const float* __restrict__ support,
                   const float* __restrict__ Wfull,
                   const float* __restrict__ bias,
                   float* __restrict__ out)
{
  __shared__ char lds[LDSB];
  const int tid  = threadIdx.x;
  const int lane = tid & 63;
  const int wv   = tid >> 6;
  const int row  = wv & 3;
  const int m    = wv >> 2;
  const int lx = lane & 15, kc = lane >> 4;
  const int bid = blockIdx.x;
  const int syq = bid & 3;
  const int xh  = (bid >> 2) & 1;
  const int yb  = (bid >> 3) & 31;
  const int b   = bid >> 8;
  const int y0 = yb * 4, x0 = xh * 64;
  const int y  = y0 + row;
  const int xq0 = xh ? 15 : 0;

  for (int e = tid; e < NPIX * 4; e += FB_NTHR)
    reinterpret_cast<f32x4*>(lds)[e] = f32x4{0.f, 0.f, 0.f, 0.f};

  bf16x8 wf[9];
  load_w(wf, Wfull, 0, m, lane);
  f32x4 va[FB_TPT], vb[FB_TPT];
  fb_stage_load(va, vb, target + (size_t)b * CIN * IMG, y0, xq0, tid);
  __syncthreads();
  fb_stage_write(va, vb, lds, y0, xq0, x0, tid);
  __syncthreads();

  f32x4 cx[4];
  #pragma unroll
  for (int n = 0; n < 4; ++n) cx[n] = f32x4{0.f, 0.f, 0.f, 0.f};
  fb_conv1(cx, lds, wf, row, lane);
  #pragma unroll
  for (int j = 0; j < 4; ++j) {
    const float bvv = bias[m * 16 + kc * 4 + j];
    #pragma unroll
    for (int n = 0; n < 4; ++n) cx[n][j] += bvv;
  }

  const float* supp0 = support + (size_t)(b * SY + syq * FB_SYC) * CIN * IMG;
  fb_stage_load(va, vb, supp0, y0, xq0, tid);
  load_w(wf, Wfull, 32, m, lane);
  __syncthreads();
  fb_stage_write(va, vb, lds, y0, xq0, x0, tid);

  f32x4 sum[4];
  #pragma unroll
  for (int n = 0; n < 4; ++n) sum[n] = f32x4{0.f, 0.f, 0.f, 0.f};
  __syncthreads();

  for (int i = 0; i < FB_SYC; ++i) {
    if (i < FB_SYC - 1)
      fb_stage_load(va, vb, supp0 + (size_t)(i + 1) * CIN * IMG, y0, xq0, tid);

    f32x4 acc[4];
    #pragma unroll
    for (int n = 0; n < 4; ++n) acc[n] = cx[n];
    fb_conv1(acc, lds, wf, row, lane);
    __syncthreads();

    if (i < FB_SYC - 1)
      fb_stage_write(va, vb, lds, y0, xq0, x0, tid);

    const int sy = syq * FB_SYC + i;
    #pragma unroll
    for (int n = 0; n < 4; ++n) {
      sum[n] += acc[n];
      const size_t basei = (size_t)NT +
          (((size_t)(b * SY + sy) * CO + m * 16 + kc * 4) * Himg + y) * Wimg +
          x0 + n * 16 + lx;
      #pragma unroll
      for (int j = 0; j < 4; ++j)
        out[basei + (size_t)j * IMG] = acc[n][j];
    }
    __syncthreads();
  }

  #pragma unroll
  for (int n = 0; n < 4; ++n) {
    const size_t baseo =
        ((size_t)(b * CO + m * 16 + kc * 4) * Himg + y) * Wimg + x0 + n * 16 + lx;
    #pragma unroll
    for (int j = 0; j < 4; ++j) {
      const float cyPart = (sum[n][j] - (float)FB_SYC * cx[n][j]) * (1.f / 32.f);
      const float v = cyPart + (syq == 0 ? cx[n][j] : 0.f);
      atomicAdd(&out[baseo + (size_t)j * IMG], v);
    }
  }
}

} // namespace

extern "C" void kernel_launch(void* const* d_in, const int* in_sizes, int n_in,
                              void* d_out, int out_size, void* d_ws, size_t ws_size,
                              hipStream_t stream)
{
  (void)in_sizes; (void)n_in; (void)out_size;
  const float* target  = (const float*)d_in[0];
  const float* support = (const float*)d_in[1];
  const float* Wfull   = (const float*)d_in[2];
  const float* bias    = (const float*)d_in[3];
  float* out = (float*)d_out;

  if (ws_size >= WS2) {
    // mean path: every output element written exactly once -> no memset, no atomics
    unsigned short* ws = (unsigned short*)d_ws;
    transform_nhwc<<<dim3((Bb * SY + Bb) * 64), 256, 0, stream>>>(target, support, ws);
    mean_k<<<dim3(512), 256, 0, stream>>>(ws);
    conv_lds<true><<<dim3(1024), 512, 0, stream>>>(ws, Wfull, bias, out);
  } else if (ws_size >= WS1) {
    unsigned short* ws = (unsigned short*)d_ws;
    hipMemsetAsync(d_out, 0, (size_t)NT * sizeof(float), stream);
    transform_nhwc<<<dim3((Bb * SY + Bb) * 64), 256, 0, stream>>>(target, support, ws);
    conv_lds<false><<<dim3(1024), 512, 0, stream>>>(ws, Wfull, bias, out);
  } else {
    hipMemsetAsync(d_out, 0, (size_t)NT * sizeof(float), stream);
    fb_cross_mfma<<<dim3(1024), FB_NTHR, 0, stream>>>(target, support, Wfull, bias, out);
  }
}